// Round 15
// baseline (74.760 us; speedup 1.0000x reference)
//
#include <hip/hip_runtime.h>
#include <math.h>
#include <stdint.h>

typedef __bf16 bf16;
typedef __bf16 bfx8 __attribute__((ext_vector_type(8)));
typedef __bf16 bfx4 __attribute__((ext_vector_type(4)));
typedef short  sh8  __attribute__((ext_vector_type(8)));
typedef float  fx4  __attribute__((ext_vector_type(4)));
typedef _Float16 h2 __attribute__((ext_vector_type(2)));
typedef _Float16 hx4 __attribute__((ext_vector_type(4)));
typedef _Float16 h8 __attribute__((ext_vector_type(8)));

#define B_ 2
#define N_ 1024
#define L_ 4096
#define C_ 256
#define H_ 8
#define D_ 32
#define KL 32
#define LOG2E 1.4426950408889634f
#define LN2 0.6931471805599453f
#define QSCALE (0.17677669529663687f * LOG2E)   // 1/sqrt(32) * log2(e), folded into Q

__device__ __forceinline__ _Float16 exp2h(_Float16 x) {
    _Float16 r; asm("v_exp_f16 %0, %1" : "=v"(r) : "v"(x)); return r;
}
__device__ __forceinline__ h2 pkrtz(float a, float b) {
    return __builtin_bit_cast(h2, __builtin_amdgcn_cvt_pkrtz(a, b));
}

// ---------- W transpose to chunked bf16: WT2[k>>3][c][8]; + MLP const prep ----------
__global__ __launch_bounds__(256)
void wtrans_kernel(const float* __restrict__ Wq, const float* __restrict__ Wk,
                   const float* __restrict__ Wv, const float* __restrict__ Wp,
                   const float* __restrict__ Wl1, const float* __restrict__ bl1,
                   const float* __restrict__ Wl2,
                   bf16* __restrict__ WTq, bf16* __restrict__ WTk,
                   bf16* __restrict__ WTv, bf16* __restrict__ WTp,
                   h2* __restrict__ mlpc) {
    const int bid = blockIdx.x;        // 64 = 4 W x 16 tiles
    const int wsel = bid >> 4;
    const int tile = bid & 15;
    const int k0 = (tile >> 2) * 64;
    const int c0 = (tile & 3) * 64;
    const float* W = wsel == 0 ? Wq : wsel == 1 ? Wk : wsel == 2 ? Wv : Wp;
    bf16* WT = wsel == 0 ? WTq : wsel == 1 ? WTk : wsel == 2 ? WTv : WTp;

    __shared__ float t_lds[64][68];
    const int tid = threadIdx.x;
    if (bid == 0) {   // MLP consts: w1h[32] (x ln2), b1h[4], w2h[4]
        if (tid < 32) {
            const int hh = tid >> 2, jp = tid & 3;
            mlpc[tid] = (h2){(_Float16)(LN2 * Wl1[hh * 8 + 2 * jp]),
                             (_Float16)(LN2 * Wl1[hh * 8 + 2 * jp + 1])};
        }
        if (tid < 4) {
            mlpc[32 + tid] = (h2){(_Float16)bl1[2 * tid], (_Float16)bl1[2 * tid + 1]};
            mlpc[36 + tid] = (h2){(_Float16)Wl2[2 * tid], (_Float16)Wl2[2 * tid + 1]};
        }
    }
    {
        const int r = tid >> 2;
        const int c4 = (tid & 3) * 16;
        const float4* src = (const float4*)(W + (size_t)(k0 + r) * C_ + c0 + c4);
        #pragma unroll
        for (int j = 0; j < 4; ++j)
            *(float4*)&t_lds[r][c4 + 4 * j] = src[j];
    }
    __syncthreads();
    const int c = tid & 63;
    const int gp = tid >> 6;
    #pragma unroll
    for (int i = 0; i < 2; ++i) {
        const int gg = gp + i * 4;
        bfx8 v;
        #pragma unroll
        for (int j = 0; j < 8; ++j) v[j] = (bf16)t_lds[gg * 8 + j][c];
        *(bfx8*)(WT + ((size_t)((k0 >> 3) + gg) * C_ + c0 + c) * 8) = v;
    }
}

// ---------- single-barrier projection GEMM: B-panel staged once, A direct ----------
// MODE 0: bf16 out (scaled). MODE 1: f16 out transposed to Vt.
template<int MODE>
__device__ __forceinline__
void proj_fast(const float* __restrict__ X, const bf16* __restrict__ WT2,
               void* __restrict__ outp, int m0, int n0, float oscale, bf16* b2s) {
    const int tid = threadIdx.x;
    const int w = tid >> 6;
    const int lane = tid & 63;
    const int r = lane & 15;
    const int g = lane >> 4;

    #pragma unroll
    for (int p = 0; p < 8; ++p) {
        const int kc = (tid >> 6) + p * 4;
        const int c = tid & 63;
        *(bfx8*)&b2s[(kc * 64 + c) * 8] = *(const bfx8*)(WT2 + ((size_t)kc * C_ + n0 + c) * 8);
    }
    __syncthreads();

    fx4 acc[4];
    #pragma unroll
    for (int t = 0; t < 4; ++t) acc[t] = (fx4){0.f, 0.f, 0.f, 0.f};

    const float* arow = X + (size_t)(m0 + w * 16 + r) * C_ + g * 8;
    #pragma unroll
    for (int kt = 0; kt < 8; ++kt) {
        const float4 x0 = *(const float4*)(arow + kt * 32);
        const float4 x1 = *(const float4*)(arow + kt * 32 + 4);
        bfx8 af;
        af[0] = (bf16)x0.x; af[1] = (bf16)x0.y; af[2] = (bf16)x0.z; af[3] = (bf16)x0.w;
        af[4] = (bf16)x1.x; af[5] = (bf16)x1.y; af[6] = (bf16)x1.z; af[7] = (bf16)x1.w;
        #pragma unroll
        for (int t = 0; t < 4; ++t) {
            const bfx8 bfr = *(const bfx8*)&b2s[((kt * 4 + g) * 64 + t * 16 + r) * 8];
            acc[t] = __builtin_amdgcn_mfma_f32_16x16x32_bf16(af, bfr, acc[t], 0, 0, 0);
        }
    }

    const int mb = m0 + w * 16;
    if (MODE == 0) {
        bf16* out = (bf16*)outp;
        #pragma unroll
        for (int t = 0; t < 4; ++t)
            #pragma unroll
            for (int reg = 0; reg < 4; ++reg)
                out[(size_t)(mb + 4 * g + reg) * C_ + n0 + t * 16 + r] = (bf16)(acc[t][reg] * oscale);
    } else {
        _Float16* out = (_Float16*)outp;   // Vt[b][h][d][l], f16
        const int bb = m0 >> 12;
        const int l0 = (m0 & (L_ - 1)) + w * 16 + 4 * g;
        #pragma unroll
        for (int t = 0; t < 4; ++t) {
            const int cc = n0 + t * 16 + r;
            hx4 v;
            #pragma unroll
            for (int reg = 0; reg < 4; ++reg) v[reg] = (_Float16)acc[t][reg];
            *(hx4*)(out + ((size_t)((bb * H_ + (cc >> 5)) * D_ + (cc & 31)) * L_ + l0)) = v;
        }
    }
}

// XCD-local mapping: within each segment, mtile = i % nm (nm % 8 == 0), coltile = i / nm,
// so the 4 blocks sharing the same A rows are ≡ mod 8 -> same XCD -> A hits local L2.
__global__ __launch_bounds__(256)
void proj_qkv_kernel(const float* __restrict__ q, const float* __restrict__ k,
                     const float* __restrict__ v,
                     const bf16* __restrict__ WTq, const bf16* __restrict__ WTk,
                     const bf16* __restrict__ WTv,
                     bf16* __restrict__ Qb, bf16* __restrict__ Kb, _Float16* __restrict__ Vt) {
    __shared__ __align__(16) bf16 b2s[32 * 64 * 8];   // 32KB
    const int bid = blockIdx.x;        // 1152 = 128 Q + 512 K + 512 V
    if (bid < 128) {
        proj_fast<0>(q, WTq, Qb, (bid & 31) * 64, (bid >> 5) * 64, QSCALE, b2s);
    } else if (bid < 640) {
        const int i = bid - 128;
        proj_fast<0>(k, WTk, Kb, (i & 127) * 64, (i >> 7) * 64, 1.0f, b2s);
    } else {
        const int i = bid - 640;
        proj_fast<1>(v, WTv, Vt, (i & 127) * 64, (i >> 7) * 64, 1.0f, b2s);
    }
}

// ---------- split-L combine (plain sums; softmax uses fixed max=0) ----------
template<int NS>
__global__ __launch_bounds__(256)
void combine_kernel(const bf16* __restrict__ pacc, const float* __restrict__ ps,
                    bf16* __restrict__ xpre) {
    const int idx = blockIdx.x * 256 + threadIdx.x;   // 65536
    const int dg = idx & 3;
    const int row = idx >> 2;
    const int n = row & (N_ - 1);
    const int bh = row >> 10;
    const int b = bh >> 3, hh = bh & 7;
    float S = 0.f;
    float X[8];
    #pragma unroll
    for (int j = 0; j < 8; ++j) X[j] = 0.f;
    #pragma unroll
    for (int sp = 0; sp < NS; ++sp) {
        S += ps[(size_t)(bh * NS + sp) * N_ + n];
        const bfx8 pv = *(const bfx8*)(pacc + ((size_t)(bh * NS + sp) * N_ + n) * D_ + dg * 8);
        #pragma unroll
        for (int j = 0; j < 8; ++j) X[j] += (float)pv[j];
    }
    const float inv = 1.0f / S;
    bfx8 v;
    #pragma unroll
    for (int j = 0; j < 8; ++j) v[j] = (bf16)(X[j] * inv);
    *(bfx8*)(xpre + (size_t)(b * N_ + n) * C_ + hh * D_ + dg * 8) = v;
}

// ---------- single-barrier out-projection: BM=64 x BN=32, A = bf16 direct ----------
__global__ __launch_bounds__(256)
void outproj_kernel(const bf16* __restrict__ xpre, const bf16* __restrict__ WTp,
                    const float* __restrict__ bp, float* __restrict__ x_out) {
    __shared__ __align__(16) bf16 b2s[32 * 32 * 8];   // 16KB
    const int m0 = (blockIdx.x & 31) * 64;
    const int n0 = (blockIdx.x >> 5) * 32;
    const int tid = threadIdx.x;
    const int w = tid >> 6, lane = tid & 63, r = lane & 15, g = lane >> 4;

    #pragma unroll
    for (int p = 0; p < 4; ++p) {
        const int kc = (tid >> 5) + p * 8;
        const int c = tid & 31;
        *(bfx8*)&b2s[(kc * 32 + c) * 8] = *(const bfx8*)(WTp + ((size_t)kc * C_ + n0 + c) * 8);
    }
    __syncthreads();

    fx4 acc[2];
    acc[0] = (fx4){0.f, 0.f, 0.f, 0.f};
    acc[1] = (fx4){0.f, 0.f, 0.f, 0.f};
    const bf16* arow = xpre + (size_t)(m0 + w * 16 + r) * C_ + g * 8;
    #pragma unroll
    for (int kt = 0; kt < 8; ++kt) {
        const bfx8 af = *(const bfx8*)(arow + kt * 32);
        #pragma unroll
        for (int t = 0; t < 2; ++t) {
            const bfx8 bfr = *(const bfx8*)&b2s[((kt * 4 + g) * 32 + t * 16 + r) * 8];
            acc[t] = __builtin_amdgcn_mfma_f32_16x16x32_bf16(af, bfr, acc[t], 0, 0, 0);
        }
    }
    const int mb = m0 + w * 16;
    #pragma unroll
    for (int t = 0; t < 2; ++t) {
        const float bv = bp[n0 + t * 16 + r];
        #pragma unroll
        for (int reg = 0; reg < 4; ++reg)
            x_out[(size_t)(mb + 4 * g + reg) * C_ + n0 + t * 16 + r] = acc[t][reg] + bv;
    }
}

// ---------- fused attention ----------
// grid B*32*NS; 8 waves = 8 heads; 32 q-rows (2 sub-tiles of 16).
// SWAPPED QK^T: S^T = mfma(K, Q) -> lane holds P-row slots (fixed n, varying l)
// = the PV A-fragment directly. No LDS readback; s_lds exists only for the
// cross-head mask MLP, layout [h][l:32][stride 17 n] of (sub0,sub1)-packed h2
// (<=2-way bank conflicts on both publish and MLP read).
// V B-frags use the matching k-slot permutation: two 8B loads (l0+4g, l0+16+4g).
// Fixed max=0 softmax; per-lane row-sum partials, epilogue reduce.
// NOTE: min-waves 4 (R9/R10: forcing 8 spills). Keep VGPR <= 64.
template<int NS>
__global__ __launch_bounds__(512, 4)
void attn_kernel(const bf16* __restrict__ Qb, const bf16* __restrict__ Kb,
                 const _Float16* __restrict__ Vt,
                 const h2* __restrict__ mlpc, const float* __restrict__ bl2,
                 bf16* __restrict__ pacc, float* __restrict__ ps,
                 float* __restrict__ maskout) {
    constexpr int LSPAN = L_ / NS;
    constexpr int NIT = LSPAN / KL;
    const int bx = blockIdx.x;
    const int split = bx % NS;
    const int rest = bx / NS;
    const int nt = rest & 31;
    const int b = rest >> 5;
    const int n0 = nt * 32;
    const int l0base = split * LSPAN;

    const int tid = threadIdx.x;
    const int h = tid >> 6;
    const int lane = tid & 63;
    const int r = lane & 15;
    const int g = lane >> 4;

    __shared__ __align__(16) short k_lds[KL * C_];   // 16KB, XOR-swizzled rows
    __shared__ __align__(16) h2 s_lds[8 * 32 * 17];  // 17KB, [h][l][n stride17]

    const float bl2v = bl2[0];
    h2 W1[32], B1[4], W2[4];
    #pragma unroll
    for (int i = 0; i < 32; ++i) W1[i] = mlpc[i];
    #pragma unroll
    for (int i = 0; i < 4; ++i) { B1[i] = mlpc[32 + i]; W2[i] = mlpc[36 + i]; }

    const bfx8 qa0 = *(const bfx8*)(Qb + ((size_t)(b * N_ + n0 + r) * C_ + h * D_ + g * 8));
    const bfx8 qa1 = *(const bfx8*)(Qb + ((size_t)(b * N_ + n0 + 16 + r) * C_ + h * D_ + g * 8));

    const int krow = tid >> 5;
    const int kcolb = (tid & 31) * 16;
    const char* Kbb = (const char*)(Kb + (size_t)b * L_ * C_);

    {   // prologue: stage K tile 0
        sh8 k0v = *(const sh8*)(Kbb + (size_t)(l0base + krow) * 512 + kcolb);
        sh8 k1v = *(const sh8*)(Kbb + (size_t)(l0base + 16 + krow) * 512 + kcolb);
        *(sh8*)((char*)k_lds + ((krow * 512 + kcolb) ^ ((krow & 7) << 4))) = k0v;
        *(sh8*)((char*)k_lds + (((krow + 16) * 512 + kcolb) ^ (((krow + 16) & 7) << 4))) = k1v;
    }

    // V pointers: rows d=r and d=16+r; k-slot permutation offsets 4g and 16+4g
    const _Float16* Vb0 = Vt + (size_t)((b * H_ + h) * D_ + r) * L_;
    const _Float16* Vb1 = Vt + (size_t)((b * H_ + h) * D_ + 16 + r) * L_;
    const int lo_off = 4 * g;
    const int hi_off = 16 + 4 * g;
    hx4 vA0 = *(const hx4*)(Vb0 + l0base + lo_off);
    hx4 vA1 = *(const hx4*)(Vb0 + l0base + hi_off);
    hx4 vB0 = *(const hx4*)(Vb1 + l0base + lo_off);
    hx4 vB1 = *(const hx4*)(Vb1 + l0base + hi_off);

    float s0r = 0.f, s1r = 0.f;   // per-lane partial row sums (reduced in epilogue)
    fx4 accA0 = {0.f,0.f,0.f,0.f}, accA1 = {0.f,0.f,0.f,0.f};
    fx4 accB0 = {0.f,0.f,0.f,0.f}, accB1 = {0.f,0.f,0.f,0.f};

    const int mn = tid >> 5;    // MLP coords: n-row (per sub), l
    const int ml = tid & 31;
    const int mbase = ml * 17 + mn;

    for (int it = 0; it < NIT; ++it) {
        const int l0 = l0base + it * KL;
        __syncthreads();   // (1) k_lds tile ready; prev MLP reads done

        // ---- S^T = K Q (log2 domain): rows l, cols n ----
        fx4 sA0, sA1, sB0, sB1;
        {
            const int byte0 = (r * 512 + h * 64 + g * 16) ^ ((r & 7) << 4);
            const int byte1 = ((r + 16) * 512 + h * 64 + g * 16) ^ (((r + 16) & 7) << 4);
            const bfx8 kb0 = __builtin_bit_cast(bfx8, *(const sh8*)((char*)k_lds + byte0));
            const bfx8 kb1 = __builtin_bit_cast(bfx8, *(const sh8*)((char*)k_lds + byte1));
            const fx4 z = {0.f, 0.f, 0.f, 0.f};
            __builtin_amdgcn_s_setprio(1);
            sA0 = __builtin_amdgcn_mfma_f32_16x16x32_bf16(kb0, qa0, z, 0, 0, 0);  // l=4g+reg,   n=r
            sA1 = __builtin_amdgcn_mfma_f32_16x16x32_bf16(kb1, qa0, z, 0, 0, 0);  // l=16+4g+reg,n=r
            sB0 = __builtin_amdgcn_mfma_f32_16x16x32_bf16(kb0, qa1, z, 0, 0, 0);  // sub1
            sB1 = __builtin_amdgcn_mfma_f32_16x16x32_bf16(kb1, qa1, z, 0, 0, 0);
            __builtin_amdgcn_s_setprio(0);
        }

        // ---- publish for MLP + in-register exp2 (P stays in regs for PV) ----
        h8 pa0, pa1;
        #pragma unroll
        for (int reg = 0; reg < 4; ++reg) {
            const h2 pk0 = pkrtz(sA0[reg], sB0[reg]);   // l = 4g+reg
            const h2 pk1 = pkrtz(sA1[reg], sB1[reg]);   // l = 16+4g+reg
            s_lds[h * 544 + (4 * g + reg) * 17 + r]      = pk0;
            s_lds[h * 544 + (16 + 4 * g + reg) * 17 + r] = pk1;
            pa0[reg]     = exp2h(pk0[0]); pa1[reg]     = exp2h(pk0[1]);
            pa0[4 + reg] = exp2h(pk1[0]); pa1[4 + reg] = exp2h(pk1[1]);
        }

        // ---- issue next K + V global loads (hide under PV + MLP) ----
        sh8 nk0, nk1;
        hx4 nA0, nA1, nB0, nB1;
        const bool have_next = (it + 1 < NIT);
        if (have_next) {
            nk0 = *(const sh8*)(Kbb + (size_t)(l0 + KL + krow) * 512 + kcolb);
            nk1 = *(const sh8*)(Kbb + (size_t)(l0 + KL + 16 + krow) * 512 + kcolb);
            nA0 = *(const hx4*)(Vb0 + l0 + KL + lo_off);
            nA1 = *(const hx4*)(Vb0 + l0 + KL + hi_off);
            nB0 = *(const hx4*)(Vb1 + l0 + KL + lo_off);
            nB1 = *(const hx4*)(Vb1 + l0 + KL + hi_off);
        }

        // ---- PV MFMAs (f16), V frags in the matching k-slot order ----
        {
            h8 vb0, vb1;
            #pragma unroll
            for (int j = 0; j < 4; ++j) {
                vb0[j] = vA0[j]; vb0[4 + j] = vA1[j];
                vb1[j] = vB0[j]; vb1[4 + j] = vB1[j];
            }
            __builtin_amdgcn_s_setprio(1);
            accA0 = __builtin_amdgcn_mfma_f32_16x16x32_f16(pa0, vb0, accA0, 0, 0, 0);
            accA1 = __builtin_amdgcn_mfma_f32_16x16x32_f16(pa0, vb1, accA1, 0, 0, 0);
            accB0 = __builtin_amdgcn_mfma_f32_16x16x32_f16(pa1, vb0, accB0, 0, 0, 0);
            accB1 = __builtin_amdgcn_mfma_f32_16x16x32_f16(pa1, vb1, accB1, 0, 0, 0);
            __builtin_amdgcn_s_setprio(0);
        }

        // ---- per-lane partial row sums (n = r fixed per lane) ----
        {
            const h2* c0 = (const h2*)&pa0;
            const h2* c1 = (const h2*)&pa1;
            const h2 q0 = (c0[0] + c0[1]) + (c0[2] + c0[3]);
            const h2 q1 = (c1[0] + c1[1]) + (c1[2] + c1[3]);
            s0r += (float)q0[0] + (float)q0[1];
            s1r += (float)q1[0] + (float)q1[1];
        }

        __syncthreads();   // (2) s_lds ready for MLP; all QK reads of k_lds done

        // ---- mask MLP (packed f16, both subs per load) ----
        {
            h2 f0[4], f1[4];
            #pragma unroll
            for (int jp = 0; jp < 4; ++jp) { f0[jp] = B1[jp]; f1[jp] = B1[jp]; }
            #pragma unroll
            for (int hh = 0; hh < 8; ++hh) {
                const h2 sv = s_lds[hh * 544 + mbase];
                const h2 s0h = (h2){sv[0], sv[0]};
                const h2 s1h = (h2){sv[1], sv[1]};
                #pragma unroll
                for (int jp = 0; jp < 4; ++jp) {
                    f0[jp] = s0h * W1[hh * 4 + jp] + f0[jp];
                    f1[jp] = s1h * W1[hh * 4 + jp] + f1[jp];
                }
            }
            const h2 z2 = (h2){(_Float16)0.f, (_Float16)0.f};
            h2 t0 = __builtin_elementwise_max(f0[0], z2) * W2[0];
            h2 t1 = __builtin_elementwise_max(f1[0], z2) * W2[0];
            #pragma unroll
            for (int jp = 1; jp < 4; ++jp) {
                t0 = __builtin_elementwise_max(f0[jp], z2) * W2[jp] + t0;
                t1 = __builtin_elementwise_max(f1[jp], z2) * W2[jp] + t1;
            }
            const float mk0 = fmaxf((float)t0[0] + (float)t0[1] + bl2v, 0.f);
            const float mk1 = fmaxf((float)t1[0] + (float)t1[1] + bl2v, 0.f);
            __builtin_nontemporal_store(mk0,
                &maskout[(size_t)(b * N_ + n0 + mn) * L_ + l0 + ml]);
            __builtin_nontemporal_store(mk1,
                &maskout[(size_t)(b * N_ + n0 + 16 + mn) * L_ + l0 + ml]);
        }

        if (have_next) {   // write next K tile; rotate V prefetch
            *(sh8*)((char*)k_lds + ((krow * 512 + kcolb) ^ ((krow & 7) << 4))) = nk0;
            *(sh8*)((char*)k_lds + (((krow + 16) * 512 + kcolb) ^ (((krow + 16) & 7) << 4))) = nk1;
            vA0 = nA0; vA1 = nA1; vB0 = nB0; vB1 = nB1;
        }
    }

    // ---- epilogue: cross-lane row-sum reduce (over g), then store partials ----
    s0r += __shfl_xor(s0r, 16, 64);
    s0r += __shfl_xor(s0r, 32, 64);
    s1r += __shfl_xor(s1r, 16, 64);
    s1r += __shfl_xor(s1r, 32, 64);

    const size_t pbase = (size_t)((b * H_ + h) * NS + split) * N_ + n0;
    #pragma unroll
    for (int reg = 0; reg < 4; ++reg) {
        const int n = 4 * g + reg;
        pacc[(pbase + n) * D_ + r]           = (bf16)accA0[reg];
        pacc[(pbase + n) * D_ + 16 + r]      = (bf16)accA1[reg];
        pacc[(pbase + 16 + n) * D_ + r]      = (bf16)accB0[reg];
        pacc[(pbase + 16 + n) * D_ + 16 + r] = (bf16)accB1[reg];
    }
    if (lane < 16) {
        ps[pbase + lane] = s0r;
        ps[pbase + 16 + lane] = s1r;
    }
}

// ---------- launch ----------
extern "C" void kernel_launch(void* const* d_in, const int* in_sizes, int n_in,
                              void* d_out, int out_size, void* d_ws, size_t ws_size,
                              hipStream_t stream) {
    const float* query = (const float*)d_in[0];
    const float* key   = (const float*)d_in[1];
    const float* value = (const float*)d_in[2];
    const float* Wq  = (const float*)d_in[5];
    const float* Wk  = (const float*)d_in[6];
    const float* Wv  = (const float*)d_in[7];
    const float* Wp  = (const float*)d_in[8];
    const float* bp  = (const float*)d_in[9];
    const float* Wl1 = (const float*)d_in[10];
    const float* bl1 = (const float*)d_in[11];
    const float* Wl2 = (const float*)d_in[12];
    const float* bl2 = (const float*)d_in[13];

    float* x_out    = (float*)d_out;                 // [B,N,C]
    float* mask_out = x_out + (size_t)B_ * N_ * C_;  // [B,N,L,1]

    char* w = (char*)d_ws;
    bf16*     WTq  = (bf16*)(w);
    bf16*     WTk  = (bf16*)(w + (128 << 10));
    bf16*     WTv  = (bf16*)(w + (256 << 10));
    bf16*     WTp  = (bf16*)(w + (384 << 10));
    h2*       mlpc = (h2*)(w + (512 << 10));         // 160B (64KB slot)
    bf16*     Qb   = (bf16*)(w + (576 << 10));       // 1MB
    bf16*     Kb   = (bf16*)(w + (1600 << 10));      // 4MB
    _Float16* Vt   = (_Float16*)(w + (5696 << 10));  // 4MB
    bf16*     xpre = (bf16*)(w + (1600 << 10));      // 1MB, aliases Kb (dead post-attn)
    bf16*     pacc = (bf16*)(w + (9792 << 10));      // NS MB

    const bool big = ws_size >= ((size_t)28224 << 10);
    const int NS = big ? 16 : 8;
    float* ps = (float*)(w + ((size_t)(9792 + NS * 1024) << 10));

    hipLaunchKernelGGL(wtrans_kernel, dim3(64), dim3(256), 0, stream,
                       Wq, Wk, Wv, Wp, Wl1, bl1, Wl2, WTq, WTk, WTv, WTp, mlpc);
    hipLaunchKernelGGL(proj_qkv_kernel, dim3(1152), dim3(256), 0, stream,
                       query, key, value, WTq, WTk, WTv, Qb, Kb, Vt);
    if (big) {
        attn_kernel<16><<<dim3(B_ * 32 * 16), dim3(512), 0, stream>>>(
            Qb, Kb, Vt, mlpc, bl2, pacc, ps, mask_out);
        combine_kernel<16><<<dim3(256), dim3(256), 0, stream>>>(pacc, ps, xpre);
    } else {
        attn_kernel<8><<<dim3(B_ * 32 * 8), dim3(512), 0, stream>>>(
            Qb, Kb, Vt, mlpc, bl2, pacc, ps, mask_out);
        combine_kernel<8><<<dim3(256), dim3(256), 0, stream>>>(pacc, ps, xpre);
    }
    hipLaunchKernelGGL(outproj_kernel, dim3(256), dim3(256), 0, stream,
                       xpre, WTp, bp, x_out);
}

// Round 16
// 73.308 us; speedup vs baseline: 1.0198x; 1.0198x over previous
//
#include <hip/hip_runtime.h>
#include <math.h>
#include <stdint.h>

typedef __bf16 bf16;
typedef __bf16 bfx8 __attribute__((ext_vector_type(8)));
typedef __bf16 bfx4 __attribute__((ext_vector_type(4)));
typedef short  sh8  __attribute__((ext_vector_type(8)));
typedef float  fx4  __attribute__((ext_vector_type(4)));
typedef _Float16 h2 __attribute__((ext_vector_type(2)));
typedef _Float16 hx4 __attribute__((ext_vector_type(4)));
typedef _Float16 h8 __attribute__((ext_vector_type(8)));

#define B_ 2
#define N_ 1024
#define L_ 4096
#define C_ 256
#define H_ 8
#define D_ 32
#define KL 32
#define LOG2E 1.4426950408889634f
#define LN2 0.6931471805599453f
#define QSCALE (0.17677669529663687f * LOG2E)   // 1/sqrt(32) * log2(e), folded into Q

__device__ __forceinline__ _Float16 exp2h(_Float16 x) {
    _Float16 r; asm("v_exp_f16 %0, %1" : "=v"(r) : "v"(x)); return r;
}
__device__ __forceinline__ h2 pkrtz(float a, float b) {
    return __builtin_bit_cast(h2, __builtin_amdgcn_cvt_pkrtz(a, b));
}

// ---------- W transpose to chunked bf16: WT2[k>>3][c][8]; + MLP const prep ----------
__global__ __launch_bounds__(256)
void wtrans_kernel(const float* __restrict__ Wq, const float* __restrict__ Wk,
                   const float* __restrict__ Wv, const float* __restrict__ Wp,
                   const float* __restrict__ Wl1, const float* __restrict__ bl1,
                   const float* __restrict__ Wl2,
                   bf16* __restrict__ WTq, bf16* __restrict__ WTk,
                   bf16* __restrict__ WTv, bf16* __restrict__ WTp,
                   h2* __restrict__ mlpc) {
    const int bid = blockIdx.x;        // 64 = 4 W x 16 tiles
    const int wsel = bid >> 4;
    const int tile = bid & 15;
    const int k0 = (tile >> 2) * 64;
    const int c0 = (tile & 3) * 64;
    const float* W = wsel == 0 ? Wq : wsel == 1 ? Wk : wsel == 2 ? Wv : Wp;
    bf16* WT = wsel == 0 ? WTq : wsel == 1 ? WTk : wsel == 2 ? WTv : WTp;

    __shared__ float t_lds[64][68];
    const int tid = threadIdx.x;
    if (bid == 0) {   // MLP consts: w1h[32] (x ln2), b1h[4], w2h[4]
        if (tid < 32) {
            const int hh = tid >> 2, jp = tid & 3;
            mlpc[tid] = (h2){(_Float16)(LN2 * Wl1[hh * 8 + 2 * jp]),
                             (_Float16)(LN2 * Wl1[hh * 8 + 2 * jp + 1])};
        }
        if (tid < 4) {
            mlpc[32 + tid] = (h2){(_Float16)bl1[2 * tid], (_Float16)bl1[2 * tid + 1]};
            mlpc[36 + tid] = (h2){(_Float16)Wl2[2 * tid], (_Float16)Wl2[2 * tid + 1]};
        }
    }
    {
        const int r = tid >> 2;
        const int c4 = (tid & 3) * 16;
        const float4* src = (const float4*)(W + (size_t)(k0 + r) * C_ + c0 + c4);
        #pragma unroll
        for (int j = 0; j < 4; ++j)
            *(float4*)&t_lds[r][c4 + 4 * j] = src[j];
    }
    __syncthreads();
    const int c = tid & 63;
    const int gp = tid >> 6;
    #pragma unroll
    for (int i = 0; i < 2; ++i) {
        const int gg = gp + i * 4;
        bfx8 v;
        #pragma unroll
        for (int j = 0; j < 8; ++j) v[j] = (bf16)t_lds[gg * 8 + j][c];
        *(bfx8*)(WT + ((size_t)((k0 >> 3) + gg) * C_ + c0 + c) * 8) = v;
    }
}

// ---------- single-barrier projection GEMM: B-panel staged once, A direct ----------
// MODE 0: bf16 out (scaled). MODE 1: f16 out transposed to Vt.
template<int MODE>
__device__ __forceinline__
void proj_fast(const float* __restrict__ X, const bf16* __restrict__ WT2,
               void* __restrict__ outp, int m0, int n0, float oscale, bf16* b2s) {
    const int tid = threadIdx.x;
    const int w = tid >> 6;
    const int lane = tid & 63;
    const int r = lane & 15;
    const int g = lane >> 4;

    #pragma unroll
    for (int p = 0; p < 8; ++p) {
        const int kc = (tid >> 6) + p * 4;
        const int c = tid & 63;
        *(bfx8*)&b2s[(kc * 64 + c) * 8] = *(const bfx8*)(WT2 + ((size_t)kc * C_ + n0 + c) * 8);
    }
    __syncthreads();

    fx4 acc[4];
    #pragma unroll
    for (int t = 0; t < 4; ++t) acc[t] = (fx4){0.f, 0.f, 0.f, 0.f};

    const float* arow = X + (size_t)(m0 + w * 16 + r) * C_ + g * 8;
    #pragma unroll
    for (int kt = 0; kt < 8; ++kt) {
        const float4 x0 = *(const float4*)(arow + kt * 32);
        const float4 x1 = *(const float4*)(arow + kt * 32 + 4);
        bfx8 af;
        af[0] = (bf16)x0.x; af[1] = (bf16)x0.y; af[2] = (bf16)x0.z; af[3] = (bf16)x0.w;
        af[4] = (bf16)x1.x; af[5] = (bf16)x1.y; af[6] = (bf16)x1.z; af[7] = (bf16)x1.w;
        #pragma unroll
        for (int t = 0; t < 4; ++t) {
            const bfx8 bfr = *(const bfx8*)&b2s[((kt * 4 + g) * 64 + t * 16 + r) * 8];
            acc[t] = __builtin_amdgcn_mfma_f32_16x16x32_bf16(af, bfr, acc[t], 0, 0, 0);
        }
    }

    const int mb = m0 + w * 16;
    if (MODE == 0) {
        bf16* out = (bf16*)outp;
        #pragma unroll
        for (int t = 0; t < 4; ++t)
            #pragma unroll
            for (int reg = 0; reg < 4; ++reg)
                out[(size_t)(mb + 4 * g + reg) * C_ + n0 + t * 16 + r] = (bf16)(acc[t][reg] * oscale);
    } else {
        _Float16* out = (_Float16*)outp;   // Vt[b][h][d][l], f16
        const int bb = m0 >> 12;
        const int l0 = (m0 & (L_ - 1)) + w * 16 + 4 * g;
        #pragma unroll
        for (int t = 0; t < 4; ++t) {
            const int cc = n0 + t * 16 + r;
            hx4 v;
            #pragma unroll
            for (int reg = 0; reg < 4; ++reg) v[reg] = (_Float16)acc[t][reg];
            *(hx4*)(out + ((size_t)((bb * H_ + (cc >> 5)) * D_ + (cc & 31)) * L_ + l0)) = v;
        }
    }
}

// XCD-local mapping: within each segment, mtile = i % nm (nm % 8 == 0), coltile = i / nm,
// so the 4 blocks sharing the same A rows are ≡ mod 8 -> same XCD -> A hits local L2.
__global__ __launch_bounds__(256)
void proj_qkv_kernel(const float* __restrict__ q, const float* __restrict__ k,
                     const float* __restrict__ v,
                     const bf16* __restrict__ WTq, const bf16* __restrict__ WTk,
                     const bf16* __restrict__ WTv,
                     bf16* __restrict__ Qb, bf16* __restrict__ Kb, _Float16* __restrict__ Vt) {
    __shared__ __align__(16) bf16 b2s[32 * 64 * 8];   // 32KB
    const int bid = blockIdx.x;        // 1152 = 128 Q + 512 K + 512 V
    if (bid < 128) {
        proj_fast<0>(q, WTq, Qb, (bid & 31) * 64, (bid >> 5) * 64, QSCALE, b2s);
    } else if (bid < 640) {
        const int i = bid - 128;
        proj_fast<0>(k, WTk, Kb, (i & 127) * 64, (i >> 7) * 64, 1.0f, b2s);
    } else {
        const int i = bid - 640;
        proj_fast<1>(v, WTv, Vt, (i & 127) * 64, (i >> 7) * 64, 1.0f, b2s);
    }
}

// ---------- split-L combine (plain sums; softmax uses fixed max=0) ----------
template<int NS>
__global__ __launch_bounds__(256)
void combine_kernel(const bf16* __restrict__ pacc, const float* __restrict__ ps,
                    bf16* __restrict__ xpre) {
    const int idx = blockIdx.x * 256 + threadIdx.x;   // 65536
    const int dg = idx & 3;
    const int row = idx >> 2;
    const int n = row & (N_ - 1);
    const int bh = row >> 10;
    const int b = bh >> 3, hh = bh & 7;
    float S = 0.f;
    float X[8];
    #pragma unroll
    for (int j = 0; j < 8; ++j) X[j] = 0.f;
    #pragma unroll
    for (int sp = 0; sp < NS; ++sp) {
        S += ps[(size_t)(bh * NS + sp) * N_ + n];
        const bfx8 pv = *(const bfx8*)(pacc + ((size_t)(bh * NS + sp) * N_ + n) * D_ + dg * 8);
        #pragma unroll
        for (int j = 0; j < 8; ++j) X[j] += (float)pv[j];
    }
    const float inv = 1.0f / S;
    bfx8 v;
    #pragma unroll
    for (int j = 0; j < 8; ++j) v[j] = (bf16)(X[j] * inv);
    *(bfx8*)(xpre + (size_t)(b * N_ + n) * C_ + hh * D_ + dg * 8) = v;
}

// ---------- single-barrier out-projection: BM=64 x BN=32, A = bf16 direct ----------
__global__ __launch_bounds__(256)
void outproj_kernel(const bf16* __restrict__ xpre, const bf16* __restrict__ WTp,
                    const float* __restrict__ bp, float* __restrict__ x_out) {
    __shared__ __align__(16) bf16 b2s[32 * 32 * 8];   // 16KB
    const int m0 = (blockIdx.x & 31) * 64;
    const int n0 = (blockIdx.x >> 5) * 32;
    const int tid = threadIdx.x;
    const int w = tid >> 6, lane = tid & 63, r = lane & 15, g = lane >> 4;

    #pragma unroll
    for (int p = 0; p < 4; ++p) {
        const int kc = (tid >> 5) + p * 8;
        const int c = tid & 31;
        *(bfx8*)&b2s[(kc * 32 + c) * 8] = *(const bfx8*)(WTp + ((size_t)kc * C_ + n0 + c) * 8);
    }
    __syncthreads();

    fx4 acc[2];
    acc[0] = (fx4){0.f, 0.f, 0.f, 0.f};
    acc[1] = (fx4){0.f, 0.f, 0.f, 0.f};
    const bf16* arow = xpre + (size_t)(m0 + w * 16 + r) * C_ + g * 8;
    #pragma unroll
    for (int kt = 0; kt < 8; ++kt) {
        const bfx8 af = *(const bfx8*)(arow + kt * 32);
        #pragma unroll
        for (int t = 0; t < 2; ++t) {
            const bfx8 bfr = *(const bfx8*)&b2s[((kt * 4 + g) * 32 + t * 16 + r) * 8];
            acc[t] = __builtin_amdgcn_mfma_f32_16x16x32_bf16(af, bfr, acc[t], 0, 0, 0);
        }
    }
    const int mb = m0 + w * 16;
    #pragma unroll
    for (int t = 0; t < 2; ++t) {
        const float bv = bp[n0 + t * 16 + r];
        #pragma unroll
        for (int reg = 0; reg < 4; ++reg)
            x_out[(size_t)(mb + 4 * g + reg) * C_ + n0 + t * 16 + r] = acc[t][reg] + bv;
    }
}

// ---------- fused attention ----------
// grid B*32*NS; 8 waves = 8 heads; 32 q-rows (2 sub-tiles of 16).
// R14 structure, but K fragments load DIRECTLY from global (no k_lds):
// per row, head h touches exactly one 64B cache line (4 g-lanes cover it),
// so the access is line-perfect and L2-resident. R9's "disaster" with this
// pattern was the (512,8) VGPR spill, not the loads (R10 post-mortem).
// Fixed max=0 softmax; f16 exp/PV; per-lane row-sum partials, epilogue reduce;
// nontemporal maskout. NOTE: min-waves 4 (spill guard). Keep VGPR <= 64.
template<int NS>
__global__ __launch_bounds__(512, 4)
void attn_kernel(const bf16* __restrict__ Qb, const bf16* __restrict__ Kb,
                 const _Float16* __restrict__ Vt,
                 const h2* __restrict__ mlpc, const float* __restrict__ bl2,
                 bf16* __restrict__ pacc, float* __restrict__ ps,
                 float* __restrict__ maskout) {
    constexpr int LSPAN = L_ / NS;
    constexpr int NIT = LSPAN / KL;
    const int bx = blockIdx.x;
    const int split = bx % NS;
    const int rest = bx / NS;
    const int nt = rest & 31;
    const int b = rest >> 5;
    const int n0 = nt * 32;
    const int l0base = split * LSPAN;

    const int tid = threadIdx.x;
    const int h = tid >> 6;
    const int lane = tid & 63;
    const int r = lane & 15;
    const int g = lane >> 4;

    __shared__ __align__(16) h2 s_lds[8 * 16 * 36];  // 18KB, (sub0,sub1) packed

    const float bl2v = bl2[0];
    h2 W1[32], B1[4], W2[4];
    #pragma unroll
    for (int i = 0; i < 32; ++i) W1[i] = mlpc[i];
    #pragma unroll
    for (int i = 0; i < 4; ++i) { B1[i] = mlpc[32 + i]; W2[i] = mlpc[36 + i]; }

    const bfx8 qa0 = *(const bfx8*)(Qb + ((size_t)(b * N_ + n0 + r) * C_ + h * D_ + g * 8));
    const bfx8 qa1 = *(const bfx8*)(Qb + ((size_t)(b * N_ + n0 + 16 + r) * C_ + h * D_ + g * 8));

    // per-wave K slice: row l -> 16B at Kb[(b*L + l)*512B + h*64 + g*16]
    const char* Kw = (const char*)Kb + (size_t)b * L_ * 512 + h * 64 + g * 16;

    const _Float16* Vb0 = Vt + (size_t)((b * H_ + h) * D_ + r) * L_ + g * 8;
    const _Float16* Vb1 = Vt + (size_t)((b * H_ + h) * D_ + 16 + r) * L_ + g * 8;

    // prologue prefetch (iter 0): K frags + V frags
    sh8 kc0 = *(const sh8*)(Kw + (size_t)(l0base + r) * 512);
    sh8 kc1 = *(const sh8*)(Kw + (size_t)(l0base + 16 + r) * 512);
    h8 vc0 = *(const h8*)(Vb0 + l0base);
    h8 vc1 = *(const h8*)(Vb1 + l0base);

    float s0r = 0.f, s1r = 0.f;   // per-lane partial row sums (reduced in epilogue)
    fx4 accA0 = {0.f,0.f,0.f,0.f}, accA1 = {0.f,0.f,0.f,0.f};
    fx4 accB0 = {0.f,0.f,0.f,0.f}, accB1 = {0.f,0.f,0.f,0.f};

    const int mn = tid >> 5;
    const int ml = tid & 31;
    const int moff = mn * 36 + (ml ^ ((mn & 3) << 3));
    const int abase = h * 576 + r * 36 + ((g ^ (r & 3)) << 3);

    for (int it = 0; it < NIT; ++it) {
        const int l0 = l0base + it * KL;

        // ---- S = Q K^T (log2 domain) from prefetched regs ----
        fx4 sA0, sA1, sB0, sB1;
        {
            const bfx8 kb0 = __builtin_bit_cast(bfx8, kc0);
            const bfx8 kb1 = __builtin_bit_cast(bfx8, kc1);
            const fx4 z = {0.f, 0.f, 0.f, 0.f};
            __builtin_amdgcn_s_setprio(1);
            sA0 = __builtin_amdgcn_mfma_f32_16x16x32_bf16(qa0, kb0, z, 0, 0, 0);
            sA1 = __builtin_amdgcn_mfma_f32_16x16x32_bf16(qa0, kb1, z, 0, 0, 0);
            sB0 = __builtin_amdgcn_mfma_f32_16x16x32_bf16(qa1, kb0, z, 0, 0, 0);
            sB1 = __builtin_amdgcn_mfma_f32_16x16x32_bf16(qa1, kb1, z, 0, 0, 0);
            __builtin_amdgcn_s_setprio(0);
        }

        // ---- issue next K + V global loads (hide under publish/MLP/PV) ----
        sh8 nk0, nk1;
        h8 nv0, nv1;
        const bool have_next = (it + 1 < NIT);
        if (have_next) {
            nk0 = *(const sh8*)(Kw + (size_t)(l0 + KL + r) * 512);
            nk1 = *(const sh8*)(Kw + (size_t)(l0 + KL + 16 + r) * 512);
            nv0 = *(const h8*)(Vb0 + l0 + KL);
            nv1 = *(const h8*)(Vb1 + l0 + KL);
        }

        __syncthreads();   // (1) prev-iter s_lds reads done everywhere

        // publish S packed (sub0,sub1): rows n=4g+reg, cols r / r+16, col-XOR by (n&3)
        #pragma unroll
        for (int reg = 0; reg < 4; ++reg) {
            const int o = h * 576 + (4 * g + reg) * 36;
            const int xr = reg << 3;
            s_lds[o + ((r) ^ xr)]      = pkrtz(sA0[reg], sB0[reg]);
            s_lds[o + ((r + 16) ^ xr)] = pkrtz(sA1[reg], sB1[reg]);
        }
        __syncthreads();   // (2) s_lds ready

        // ---- mask MLP (packed f16, both subs per load) ----
        {
            h2 f0[4], f1[4];
            #pragma unroll
            for (int jp = 0; jp < 4; ++jp) { f0[jp] = B1[jp]; f1[jp] = B1[jp]; }
            #pragma unroll
            for (int hh = 0; hh < 8; ++hh) {
                const h2 sv = s_lds[hh * 576 + moff];
                const h2 s0h = (h2){sv[0], sv[0]};
                const h2 s1h = (h2){sv[1], sv[1]};
                #pragma unroll
                for (int jp = 0; jp < 4; ++jp) {
                    f0[jp] = s0h * W1[hh * 4 + jp] + f0[jp];
                    f1[jp] = s1h * W1[hh * 4 + jp] + f1[jp];
                }
            }
            const h2 z2 = (h2){(_Float16)0.f, (_Float16)0.f};
            h2 t0 = __builtin_elementwise_max(f0[0], z2) * W2[0];
            h2 t1 = __builtin_elementwise_max(f1[0], z2) * W2[0];
            #pragma unroll
            for (int jp = 1; jp < 4; ++jp) {
                t0 = __builtin_elementwise_max(f0[jp], z2) * W2[jp] + t0;
                t1 = __builtin_elementwise_max(f1[jp], z2) * W2[jp] + t1;
            }
            const float mk0 = fmaxf((float)t0[0] + (float)t0[1] + bl2v, 0.f);
            const float mk1 = fmaxf((float)t1[0] + (float)t1[1] + bl2v, 0.f);
            __builtin_nontemporal_store(mk0,
                &maskout[(size_t)(b * N_ + n0 + mn) * L_ + l0 + ml]);
            __builtin_nontemporal_store(mk1,
                &maskout[(size_t)(b * N_ + n0 + 16 + mn) * L_ + l0 + ml]);
        }

        // ---- A-layout S readback: row r, l = 8g..8g+7, both subs interleaved ----
        const h8 sv0 = *(const h8*)&s_lds[abase];       // (s0,s1) x l0..l3
        const h8 sv1 = *(const h8*)&s_lds[abase + 4];   // (s0,s1) x l4..l7

        // ---- softmax numerators, fixed max = 0: p = exp2(s), all in f16 ----
        h8 pa0, pa1;
        pa0[0] = exp2h(sv0[0]); pa0[1] = exp2h(sv0[2]);
        pa0[2] = exp2h(sv0[4]); pa0[3] = exp2h(sv0[6]);
        pa0[4] = exp2h(sv1[0]); pa0[5] = exp2h(sv1[2]);
        pa0[6] = exp2h(sv1[4]); pa0[7] = exp2h(sv1[6]);
        pa1[0] = exp2h(sv0[1]); pa1[1] = exp2h(sv0[3]);
        pa1[2] = exp2h(sv0[5]); pa1[3] = exp2h(sv0[7]);
        pa1[4] = exp2h(sv1[1]); pa1[5] = exp2h(sv1[3]);
        pa1[6] = exp2h(sv1[5]); pa1[7] = exp2h(sv1[7]);
        {   // packed partial sums -> per-lane accumulators (no shuffles in loop)
            const h2* c0 = (const h2*)&pa0;
            const h2* c1 = (const h2*)&pa1;
            const h2 q0 = (c0[0] + c0[1]) + (c0[2] + c0[3]);
            const h2 q1 = (c1[0] + c1[1]) + (c1[2] + c1[3]);
            s0r += (float)q0[0] + (float)q0[1];
            s1r += (float)q1[0] + (float)q1[1];
        }

        // ---- PV MFMAs (f16) ----
        __builtin_amdgcn_s_setprio(1);
        accA0 = __builtin_amdgcn_mfma_f32_16x16x32_f16(pa0, vc0, accA0, 0, 0, 0);
        accA1 = __builtin_amdgcn_mfma_f32_16x16x32_f16(pa0, vc1, accA1, 0, 0, 0);
        accB0 = __builtin_amdgcn_mfma_f32_16x16x32_f16(pa1, vc0, accB0, 0, 0, 0);
        accB1 = __builtin_amdgcn_mfma_f32_16x16x32_f16(pa1, vc1, accB1, 0, 0, 0);
        __builtin_amdgcn_s_setprio(0);

        if (have_next) {   // rotate prefetch registers
            kc0 = nk0; kc1 = nk1;
            vc0 = nv0; vc1 = nv1;
        }
    }

    // ---- epilogue: single cross-lane row-sum reduce, then store partials ----
    s0r += __shfl_xor(s0r, 16, 64);
    s0r += __shfl_xor(s0r, 32, 64);
    s1r += __shfl_xor(s1r, 16, 64);
    s1r += __shfl_xor(s1r, 32, 64);

    const size_t pbase = (size_t)((b * H_ + h) * NS + split) * N_ + n0;
    #pragma unroll
    for (int reg = 0; reg < 4; ++reg) {
        const int n = 4 * g + reg;
        pacc[(pbase + n) * D_ + r]           = (bf16)accA0[reg];
        pacc[(pbase + n) * D_ + 16 + r]      = (bf16)accA1[reg];
        pacc[(pbase + 16 + n) * D_ + r]      = (bf16)accB0[reg];
        pacc[(pbase + 16 + n) * D_ + 16 + r] = (bf16)accB1[reg];
    }
    if (lane < 16) {
        ps[pbase + lane] = s0r;
        ps[pbase + 16 + lane] = s1r;
    }
}

// ---------- launch ----------
extern "C" void kernel_launch(void* const* d_in, const int* in_sizes, int n_in,
                              void* d_out, int out_size, void* d_ws, size_t ws_size,
                              hipStream_t stream) {
    const float* query = (const float*)d_in[0];
    const float* key   = (const float*)d_in[1];
    const float* value = (const float*)d_in[2];
    const float* Wq  = (const float*)d_in[5];
    const float* Wk  = (const float*)d_in[6];
    const float* Wv  = (const float*)d_in[7];
    const float* Wp  = (const float*)d_in[8];
    const float* bp  = (const float*)d_in[9];
    const float* Wl1 = (const float*)d_in[10];
    const float* bl1 = (const float*)d_in[11];
    const float* Wl2 = (const float*)d_in[12];
    const float* bl2 = (const float*)d_in[13];

    float* x_out    = (float*)d_out;                 // [B,N,C]
    float* mask_out = x_out + (size_t)B_ * N_ * C_;  // [B,N,L,1]

    char* w = (char*)d_ws;
    bf16*     WTq  = (bf16*)(w);
    bf16*     WTk  = (bf16*)(w + (128 << 10));
    bf16*     WTv  = (bf16*)(w + (256 << 10));
    bf16*     WTp  = (bf16*)(w + (384 << 10));
    h2*       mlpc = (h2*)(w + (512 << 10));         // 160B (64KB slot)
    bf16*     Qb   = (bf16*)(w + (576 << 10));       // 1MB
    bf16*     Kb   = (bf16*)(w + (1600 << 10));      // 4MB
    _Float16* Vt   = (_Float16*)(w + (5696 << 10));  // 4MB
    bf16*     xpre = (bf16*)(w + (1600 << 10));      // 1MB, aliases Kb (dead post-attn)
    bf16*     pacc = (bf16*)(w + (9792 << 10));      // NS MB

    const bool big = ws_size >= ((size_t)28224 << 10);
    const int NS = big ? 16 : 8;
    float* ps = (float*)(w + ((size_t)(9792 + NS * 1024) << 10));

    hipLaunchKernelGGL(wtrans_kernel, dim3(64), dim3(256), 0, stream,
                       Wq, Wk, Wv, Wp, Wl1, bl1, Wl2, WTq, WTk, WTv, WTp, mlpc);
    hipLaunchKernelGGL(proj_qkv_kernel, dim3(1152), dim3(256), 0, stream,
                       query, key, value, WTq, WTk, WTv, Qb, Kb, Vt);
    if (big) {
        attn_kernel<16><<<dim3(B_ * 32 * 16), dim3(512), 0, stream>>>(
            Qb, Kb, Vt, mlpc, bl2, pacc, ps, mask_out);
        combine_kernel<16><<<dim3(256), dim3(256), 0, stream>>>(pacc, ps, xpre);
    } else {
        attn_kernel<8><<<dim3(B_ * 32 * 8), dim3(512), 0, stream>>>(
            Qb, Kb, Vt, mlpc, bl2, pacc, ps, mask_out);
        combine_kernel<8><<<dim3(256), dim3(256), 0, stream>>>(pacc, ps, xpre);
    }
    hipLaunchKernelGGL(outproj_kernel, dim3(256), dim3(256), 0, stream,
                       xpre, WTp, bp, x_out);
}

// Round 17
// 66.525 us; speedup vs baseline: 1.1238x; 1.1020x over previous
//
#include <hip/hip_runtime.h>
#include <math.h>
#include <stdint.h>

typedef __bf16 bf16;
typedef __bf16 bfx8 __attribute__((ext_vector_type(8)));
typedef __bf16 bfx4 __attribute__((ext_vector_type(4)));
typedef short  sh8  __attribute__((ext_vector_type(8)));
typedef float  fx4  __attribute__((ext_vector_type(4)));
typedef _Float16 h2 __attribute__((ext_vector_type(2)));
typedef _Float16 hx4 __attribute__((ext_vector_type(4)));
typedef _Float16 h8 __attribute__((ext_vector_type(8)));

#define B_ 2
#define N_ 1024
#define L_ 4096
#define C_ 256
#define H_ 8
#define D_ 32
#define KL 32
#define LOG2E 1.4426950408889634f
#define LN2 0.6931471805599453f
#define QSCALE (0.17677669529663687f * LOG2E)   // 1/sqrt(32) * log2(e), folded into Q

__device__ __forceinline__ _Float16 exp2h(_Float16 x) {
    _Float16 r; asm("v_exp_f16 %0, %1" : "=v"(r) : "v"(x)); return r;
}
__device__ __forceinline__ h2 pkrtz(float a, float b) {
    return __builtin_bit_cast(h2, __builtin_amdgcn_cvt_pkrtz(a, b));
}

// ---------- W transpose to chunked bf16: WT2[k>>3][c][8]; + MLP const prep ----------
__global__ __launch_bounds__(256)
void wtrans_kernel(const float* __restrict__ Wq, const float* __restrict__ Wk,
                   const float* __restrict__ Wv, const float* __restrict__ Wp,
                   const float* __restrict__ Wl1, const float* __restrict__ bl1,
                   const float* __restrict__ Wl2,
                   bf16* __restrict__ WTq, bf16* __restrict__ WTk,
                   bf16* __restrict__ WTv, bf16* __restrict__ WTp,
                   h2* __restrict__ mlpc) {
    const int bid = blockIdx.x;        // 64 = 4 W x 16 tiles
    const int wsel = bid >> 4;
    const int tile = bid & 15;
    const int k0 = (tile >> 2) * 64;
    const int c0 = (tile & 3) * 64;
    const float* W = wsel == 0 ? Wq : wsel == 1 ? Wk : wsel == 2 ? Wv : Wp;
    bf16* WT = wsel == 0 ? WTq : wsel == 1 ? WTk : wsel == 2 ? WTv : WTp;

    __shared__ float t_lds[64][68];
    const int tid = threadIdx.x;
    if (bid == 0) {   // MLP consts: w1h[32] (x ln2), b1h[4], w2h[4]
        if (tid < 32) {
            const int hh = tid >> 2, jp = tid & 3;
            mlpc[tid] = (h2){(_Float16)(LN2 * Wl1[hh * 8 + 2 * jp]),
                             (_Float16)(LN2 * Wl1[hh * 8 + 2 * jp + 1])};
        }
        if (tid < 4) {
            mlpc[32 + tid] = (h2){(_Float16)bl1[2 * tid], (_Float16)bl1[2 * tid + 1]};
            mlpc[36 + tid] = (h2){(_Float16)Wl2[2 * tid], (_Float16)Wl2[2 * tid + 1]};
        }
    }
    {
        const int r = tid >> 2;
        const int c4 = (tid & 3) * 16;
        const float4* src = (const float4*)(W + (size_t)(k0 + r) * C_ + c0 + c4);
        #pragma unroll
        for (int j = 0; j < 4; ++j)
            *(float4*)&t_lds[r][c4 + 4 * j] = src[j];
    }
    __syncthreads();
    const int c = tid & 63;
    const int gp = tid >> 6;
    #pragma unroll
    for (int i = 0; i < 2; ++i) {
        const int gg = gp + i * 4;
        bfx8 v;
        #pragma unroll
        for (int j = 0; j < 8; ++j) v[j] = (bf16)t_lds[gg * 8 + j][c];
        *(bfx8*)(WT + ((size_t)((k0 >> 3) + gg) * C_ + c0 + c) * 8) = v;
    }
}

// ---------- single-barrier projection GEMM: B-panel staged once, A direct ----------
// MODE 0: bf16 out (scaled). MODE 1: f16 out transposed to Vt.
template<int MODE>
__device__ __forceinline__
void proj_fast(const float* __restrict__ X, const bf16* __restrict__ WT2,
               void* __restrict__ outp, int m0, int n0, float oscale, bf16* b2s) {
    const int tid = threadIdx.x;
    const int w = tid >> 6;
    const int lane = tid & 63;
    const int r = lane & 15;
    const int g = lane >> 4;

    #pragma unroll
    for (int p = 0; p < 8; ++p) {
        const int kc = (tid >> 6) + p * 4;
        const int c = tid & 63;
        *(bfx8*)&b2s[(kc * 64 + c) * 8] = *(const bfx8*)(WT2 + ((size_t)kc * C_ + n0 + c) * 8);
    }
    __syncthreads();

    fx4 acc[4];
    #pragma unroll
    for (int t = 0; t < 4; ++t) acc[t] = (fx4){0.f, 0.f, 0.f, 0.f};

    const float* arow = X + (size_t)(m0 + w * 16 + r) * C_ + g * 8;
    #pragma unroll
    for (int kt = 0; kt < 8; ++kt) {
        const float4 x0 = *(const float4*)(arow + kt * 32);
        const float4 x1 = *(const float4*)(arow + kt * 32 + 4);
        bfx8 af;
        af[0] = (bf16)x0.x; af[1] = (bf16)x0.y; af[2] = (bf16)x0.z; af[3] = (bf16)x0.w;
        af[4] = (bf16)x1.x; af[5] = (bf16)x1.y; af[6] = (bf16)x1.z; af[7] = (bf16)x1.w;
        #pragma unroll
        for (int t = 0; t < 4; ++t) {
            const bfx8 bfr = *(const bfx8*)&b2s[((kt * 4 + g) * 64 + t * 16 + r) * 8];
            acc[t] = __builtin_amdgcn_mfma_f32_16x16x32_bf16(af, bfr, acc[t], 0, 0, 0);
        }
    }

    const int mb = m0 + w * 16;
    if (MODE == 0) {
        bf16* out = (bf16*)outp;
        #pragma unroll
        for (int t = 0; t < 4; ++t)
            #pragma unroll
            for (int reg = 0; reg < 4; ++reg)
                out[(size_t)(mb + 4 * g + reg) * C_ + n0 + t * 16 + r] = (bf16)(acc[t][reg] * oscale);
    } else {
        _Float16* out = (_Float16*)outp;   // Vt[b][h][d][l], f16
        const int bb = m0 >> 12;
        const int l0 = (m0 & (L_ - 1)) + w * 16 + 4 * g;
        #pragma unroll
        for (int t = 0; t < 4; ++t) {
            const int cc = n0 + t * 16 + r;
            hx4 v;
            #pragma unroll
            for (int reg = 0; reg < 4; ++reg) v[reg] = (_Float16)acc[t][reg];
            *(hx4*)(out + ((size_t)((bb * H_ + (cc >> 5)) * D_ + (cc & 31)) * L_ + l0)) = v;
        }
    }
}

// XCD-local mapping: within each segment, mtile = i % nm (nm % 8 == 0), coltile = i / nm,
// so the 4 blocks sharing the same A rows are ≡ mod 8 -> same XCD -> A hits local L2.
__global__ __launch_bounds__(256)
void proj_qkv_kernel(const float* __restrict__ q, const float* __restrict__ k,
                     const float* __restrict__ v,
                     const bf16* __restrict__ WTq, const bf16* __restrict__ WTk,
                     const bf16* __restrict__ WTv,
                     bf16* __restrict__ Qb, bf16* __restrict__ Kb, _Float16* __restrict__ Vt) {
    __shared__ __align__(16) bf16 b2s[32 * 64 * 8];   // 32KB
    const int bid = blockIdx.x;        // 1152 = 128 Q + 512 K + 512 V
    if (bid < 128) {
        proj_fast<0>(q, WTq, Qb, (bid & 31) * 64, (bid >> 5) * 64, QSCALE, b2s);
    } else if (bid < 640) {
        const int i = bid - 128;
        proj_fast<0>(k, WTk, Kb, (i & 127) * 64, (i >> 7) * 64, 1.0f, b2s);
    } else {
        const int i = bid - 640;
        proj_fast<1>(v, WTv, Vt, (i & 127) * 64, (i >> 7) * 64, 1.0f, b2s);
    }
}

// ---------- split-L combine (plain sums; softmax uses fixed max=0) ----------
template<int NS>
__global__ __launch_bounds__(256)
void combine_kernel(const bf16* __restrict__ pacc, const float* __restrict__ ps,
                    bf16* __restrict__ xpre) {
    const int idx = blockIdx.x * 256 + threadIdx.x;   // 65536
    const int dg = idx & 3;
    const int row = idx >> 2;
    const int n = row & (N_ - 1);
    const int bh = row >> 10;
    const int b = bh >> 3, hh = bh & 7;
    float S = 0.f;
    float X[8];
    #pragma unroll
    for (int j = 0; j < 8; ++j) X[j] = 0.f;
    #pragma unroll
    for (int sp = 0; sp < NS; ++sp) {
        S += ps[(size_t)(bh * NS + sp) * N_ + n];
        const bfx8 pv = *(const bfx8*)(pacc + ((size_t)(bh * NS + sp) * N_ + n) * D_ + dg * 8);
        #pragma unroll
        for (int j = 0; j < 8; ++j) X[j] += (float)pv[j];
    }
    const float inv = 1.0f / S;
    bfx8 v;
    #pragma unroll
    for (int j = 0; j < 8; ++j) v[j] = (bf16)(X[j] * inv);
    *(bfx8*)(xpre + (size_t)(b * N_ + n) * C_ + hh * D_ + dg * 8) = v;
}

// ---------- single-barrier out-projection: BM=64 x BN=32, A = bf16 direct ----------
__global__ __launch_bounds__(256)
void outproj_kernel(const bf16* __restrict__ xpre, const bf16* __restrict__ WTp,
                    const float* __restrict__ bp, float* __restrict__ x_out) {
    __shared__ __align__(16) bf16 b2s[32 * 32 * 8];   // 16KB
    const int m0 = (blockIdx.x & 31) * 64;
    const int n0 = (blockIdx.x >> 5) * 32;
    const int tid = threadIdx.x;
    const int w = tid >> 6, lane = tid & 63, r = lane & 15, g = lane >> 4;

    #pragma unroll
    for (int p = 0; p < 4; ++p) {
        const int kc = (tid >> 5) + p * 8;
        const int c = tid & 31;
        *(bfx8*)&b2s[(kc * 32 + c) * 8] = *(const bfx8*)(WTp + ((size_t)kc * C_ + n0 + c) * 8);
    }
    __syncthreads();

    fx4 acc[2];
    acc[0] = (fx4){0.f, 0.f, 0.f, 0.f};
    acc[1] = (fx4){0.f, 0.f, 0.f, 0.f};
    const bf16* arow = xpre + (size_t)(m0 + w * 16 + r) * C_ + g * 8;
    #pragma unroll
    for (int kt = 0; kt < 8; ++kt) {
        const bfx8 af = *(const bfx8*)(arow + kt * 32);
        #pragma unroll
        for (int t = 0; t < 2; ++t) {
            const bfx8 bfr = *(const bfx8*)&b2s[((kt * 4 + g) * 32 + t * 16 + r) * 8];
            acc[t] = __builtin_amdgcn_mfma_f32_16x16x32_bf16(af, bfr, acc[t], 0, 0, 0);
        }
    }
    const int mb = m0 + w * 16;
    #pragma unroll
    for (int t = 0; t < 2; ++t) {
        const float bv = bp[n0 + t * 16 + r];
        #pragma unroll
        for (int reg = 0; reg < 4; ++reg)
            x_out[(size_t)(mb + 4 * g + reg) * C_ + n0 + t * 16 + r] = acc[t][reg] + bv;
    }
}

// ---------- fused attention (R14 configuration — empirical Pareto point) ----------
// grid B*32*NS; 8 waves = 8 heads; 32 q-rows (2 sub-tiles of 16).
// K staged in LDS (XOR swizzle): QK depends only on lgkmcnt, not vmcnt —
// direct-global K (R16) exposed L2 latency serialized behind the store queue.
// Fixed max=0 softmax; f16 exp/PV; per-lane row-sum partials, epilogue reduce;
// nontemporal maskout. NOTE: min-waves 4 (R9/R10: forcing 8 spills, +250MB
// scratch traffic). Keep VGPR <= 64 for 4-block/CU residency.
template<int NS>
__global__ __launch_bounds__(512, 4)
void attn_kernel(const bf16* __restrict__ Qb, const bf16* __restrict__ Kb,
                 const _Float16* __restrict__ Vt,
                 const h2* __restrict__ mlpc, const float* __restrict__ bl2,
                 bf16* __restrict__ pacc, float* __restrict__ ps,
                 float* __restrict__ maskout) {
    constexpr int LSPAN = L_ / NS;
    constexpr int NIT = LSPAN / KL;
    const int bx = blockIdx.x;
    const int split = bx % NS;
    const int rest = bx / NS;
    const int nt = rest & 31;
    const int b = rest >> 5;
    const int n0 = nt * 32;
    const int l0base = split * LSPAN;

    const int tid = threadIdx.x;
    const int h = tid >> 6;
    const int lane = tid & 63;
    const int r = lane & 15;
    const int g = lane >> 4;

    __shared__ __align__(16) short k_lds[KL * C_];   // 16KB, XOR-swizzled rows
    __shared__ __align__(16) h2 s_lds[8 * 16 * 36];  // 18KB, (sub0,sub1) packed

    const float bl2v = bl2[0];
    h2 W1[32], B1[4], W2[4];
    #pragma unroll
    for (int i = 0; i < 32; ++i) W1[i] = mlpc[i];
    #pragma unroll
    for (int i = 0; i < 4; ++i) { B1[i] = mlpc[32 + i]; W2[i] = mlpc[36 + i]; }

    const bfx8 qa0 = *(const bfx8*)(Qb + ((size_t)(b * N_ + n0 + r) * C_ + h * D_ + g * 8));
    const bfx8 qa1 = *(const bfx8*)(Qb + ((size_t)(b * N_ + n0 + 16 + r) * C_ + h * D_ + g * 8));

    const int krow = tid >> 5;
    const int kcolb = (tid & 31) * 16;
    const char* Kbb = (const char*)(Kb + (size_t)b * L_ * C_);

    {   // prologue: stage K tile 0
        sh8 k0v = *(const sh8*)(Kbb + (size_t)(l0base + krow) * 512 + kcolb);
        sh8 k1v = *(const sh8*)(Kbb + (size_t)(l0base + 16 + krow) * 512 + kcolb);
        *(sh8*)((char*)k_lds + ((krow * 512 + kcolb) ^ ((krow & 7) << 4))) = k0v;
        *(sh8*)((char*)k_lds + (((krow + 16) * 512 + kcolb) ^ (((krow + 16) & 7) << 4))) = k1v;
    }

    const _Float16* Vb0 = Vt + (size_t)((b * H_ + h) * D_ + r) * L_ + g * 8;
    const _Float16* Vb1 = Vt + (size_t)((b * H_ + h) * D_ + 16 + r) * L_ + g * 8;
    h8 vc0 = *(const h8*)(Vb0 + l0base);
    h8 vc1 = *(const h8*)(Vb1 + l0base);

    float s0r = 0.f, s1r = 0.f;   // per-lane partial row sums (reduced in epilogue)
    fx4 accA0 = {0.f,0.f,0.f,0.f}, accA1 = {0.f,0.f,0.f,0.f};
    fx4 accB0 = {0.f,0.f,0.f,0.f}, accB1 = {0.f,0.f,0.f,0.f};

    const int mn = tid >> 5;
    const int ml = tid & 31;
    const int moff = mn * 36 + (ml ^ ((mn & 3) << 3));
    const int abase = h * 576 + r * 36 + ((g ^ (r & 3)) << 3);

    for (int it = 0; it < NIT; ++it) {
        const int l0 = l0base + it * KL;
        __syncthreads();   // (1) k_lds tile ready; prev s_lds reads done

        // ---- S = Q K^T (log2 domain) ----
        fx4 sA0, sA1, sB0, sB1;
        {
            const int byte0 = (r * 512 + h * 64 + g * 16) ^ ((r & 7) << 4);
            const int byte1 = ((r + 16) * 512 + h * 64 + g * 16) ^ (((r + 16) & 7) << 4);
            const bfx8 kb0 = __builtin_bit_cast(bfx8, *(const sh8*)((char*)k_lds + byte0));
            const bfx8 kb1 = __builtin_bit_cast(bfx8, *(const sh8*)((char*)k_lds + byte1));
            const fx4 z = {0.f, 0.f, 0.f, 0.f};
            __builtin_amdgcn_s_setprio(1);
            sA0 = __builtin_amdgcn_mfma_f32_16x16x32_bf16(qa0, kb0, z, 0, 0, 0);
            sA1 = __builtin_amdgcn_mfma_f32_16x16x32_bf16(qa0, kb1, z, 0, 0, 0);
            sB0 = __builtin_amdgcn_mfma_f32_16x16x32_bf16(qa1, kb0, z, 0, 0, 0);
            sB1 = __builtin_amdgcn_mfma_f32_16x16x32_bf16(qa1, kb1, z, 0, 0, 0);
            __builtin_amdgcn_s_setprio(0);
        }
        // publish S packed (sub0,sub1): rows n=4g+reg, cols r / r+16, col-XOR by (n&3)
        #pragma unroll
        for (int reg = 0; reg < 4; ++reg) {
            const int o = h * 576 + (4 * g + reg) * 36;
            const int xr = reg << 3;
            s_lds[o + ((r) ^ xr)]      = pkrtz(sA0[reg], sB0[reg]);
            s_lds[o + ((r + 16) ^ xr)] = pkrtz(sA1[reg], sB1[reg]);
        }
        __syncthreads();   // (2) s_lds ready; k_lds consumed

        // ---- issue next K + V global loads ----
        sh8 nk0, nk1;
        h8 nv0, nv1;
        const bool have_next = (it + 1 < NIT);
        if (have_next) {
            nk0 = *(const sh8*)(Kbb + (size_t)(l0 + KL + krow) * 512 + kcolb);
            nk1 = *(const sh8*)(Kbb + (size_t)(l0 + KL + 16 + krow) * 512 + kcolb);
            nv0 = *(const h8*)(Vb0 + l0 + KL);
            nv1 = *(const h8*)(Vb1 + l0 + KL);
        }

        // ---- mask MLP (packed f16, both subs per load) ----
        {
            h2 f0[4], f1[4];
            #pragma unroll
            for (int jp = 0; jp < 4; ++jp) { f0[jp] = B1[jp]; f1[jp] = B1[jp]; }
            #pragma unroll
            for (int hh = 0; hh < 8; ++hh) {
                const h2 sv = s_lds[hh * 576 + moff];
                const h2 s0h = (h2){sv[0], sv[0]};
                const h2 s1h = (h2){sv[1], sv[1]};
                #pragma unroll
                for (int jp = 0; jp < 4; ++jp) {
                    f0[jp] = s0h * W1[hh * 4 + jp] + f0[jp];
                    f1[jp] = s1h * W1[hh * 4 + jp] + f1[jp];
                }
            }
            const h2 z2 = (h2){(_Float16)0.f, (_Float16)0.f};
            h2 t0 = __builtin_elementwise_max(f0[0], z2) * W2[0];
            h2 t1 = __builtin_elementwise_max(f1[0], z2) * W2[0];
            #pragma unroll
            for (int jp = 1; jp < 4; ++jp) {
                t0 = __builtin_elementwise_max(f0[jp], z2) * W2[jp] + t0;
                t1 = __builtin_elementwise_max(f1[jp], z2) * W2[jp] + t1;
            }
            const float mk0 = fmaxf((float)t0[0] + (float)t0[1] + bl2v, 0.f);
            const float mk1 = fmaxf((float)t1[0] + (float)t1[1] + bl2v, 0.f);
            __builtin_nontemporal_store(mk0,
                &maskout[(size_t)(b * N_ + n0 + mn) * L_ + l0 + ml]);
            __builtin_nontemporal_store(mk1,
                &maskout[(size_t)(b * N_ + n0 + 16 + mn) * L_ + l0 + ml]);
        }

        // ---- A-layout S readback: row r, l = 8g..8g+7, both subs interleaved ----
        const h8 sv0 = *(const h8*)&s_lds[abase];       // (s0,s1) x l0..l3
        const h8 sv1 = *(const h8*)&s_lds[abase + 4];   // (s0,s1) x l4..l7

        // ---- softmax numerators, fixed max = 0: p = exp2(s), all in f16 ----
        h8 pa0, pa1;
        pa0[0] = exp2h(sv0[0]); pa0[1] = exp2h(sv0[2]);
        pa0[2] = exp2h(sv0[4]); pa0[3] = exp2h(sv0[6]);
        pa0[4] = exp2h(sv1[0]); pa0[5] = exp2h(sv1[2]);
        pa0[6] = exp2h(sv1[4]); pa0[7] = exp2h(sv1[6]);
        pa1[0] = exp2h(sv0[1]); pa1[1] = exp2h(sv0[3]);
        pa1[2] = exp2h(sv0[5]); pa1[3] = exp2h(sv0[7]);
        pa1[4] = exp2h(sv1[1]); pa1[5] = exp2h(sv1[3]);
        pa1[6] = exp2h(sv1[5]); pa1[7] = exp2h(sv1[7]);
        {   // packed partial sums -> per-lane accumulators (no shuffles in loop)
            const h2* c0 = (const h2*)&pa0;
            const h2* c1 = (const h2*)&pa1;
            const h2 q0 = (c0[0] + c0[1]) + (c0[2] + c0[3]);
            const h2 q1 = (c1[0] + c1[1]) + (c1[2] + c1[3]);
            s0r += (float)q0[0] + (float)q0[1];
            s1r += (float)q1[0] + (float)q1[1];
        }

        // ---- PV MFMAs (f16) ----
        __builtin_amdgcn_s_setprio(1);
        accA0 = __builtin_amdgcn_mfma_f32_16x16x32_f16(pa0, vc0, accA0, 0, 0, 0);
        accA1 = __builtin_amdgcn_mfma_f32_16x16x32_f16(pa0, vc1, accA1, 0, 0, 0);
        accB0 = __builtin_amdgcn_mfma_f32_16x16x32_f16(pa1, vc0, accB0, 0, 0, 0);
        accB1 = __builtin_amdgcn_mfma_f32_16x16x32_f16(pa1, vc1, accB1, 0, 0, 0);
        __builtin_amdgcn_s_setprio(0);

        if (have_next) {   // write next K tile; rotate V prefetch
            *(sh8*)((char*)k_lds + ((krow * 512 + kcolb) ^ ((krow & 7) << 4))) = nk0;
            *(sh8*)((char*)k_lds + (((krow + 16) * 512 + kcolb) ^ (((krow + 16) & 7) << 4))) = nk1;
            vc0 = nv0; vc1 = nv1;
        }
    }

    // ---- epilogue: single cross-lane row-sum reduce, then store partials ----
    s0r += __shfl_xor(s0r, 16, 64);
    s0r += __shfl_xor(s0r, 32, 64);
    s1r += __shfl_xor(s1r, 16, 64);
    s1r += __shfl_xor(s1r, 32, 64);

    const size_t pbase = (size_t)((b * H_ + h) * NS + split) * N_ + n0;
    #pragma unroll
    for (int reg = 0; reg < 4; ++reg) {
        const int n = 4 * g + reg;
        pacc[(pbase + n) * D_ + r]           = (bf16)accA0[reg];
        pacc[(pbase + n) * D_ + 16 + r]      = (bf16)accA1[reg];
        pacc[(pbase + 16 + n) * D_ + r]      = (bf16)accB0[reg];
        pacc[(pbase + 16 + n) * D_ + 16 + r] = (bf16)accB1[reg];
    }
    if (lane < 16) {
        ps[pbase + lane] = s0r;
        ps[pbase + 16 + lane] = s1r;
    }
}

// ---------- launch ----------
extern "C" void kernel_launch(void* const* d_in, const int* in_sizes, int n_in,
                              void* d_out, int out_size, void* d_ws, size_t ws_size,
                              hipStream_t stream) {
    const float* query = (const float*)d_in[0];
    const float* key   = (const float*)d_in[1];
    const float* value = (const float*)d_in[2];
    const float* Wq  = (const float*)d_in[5];
    const float* Wk  = (const float*)d_in[6];
    const float* Wv  = (const float*)d_in[7];
    const float* Wp  = (const float*)d_in[8];
    const float* bp  = (const float*)d_in[9];
    const float* Wl1 = (const float*)d_in[10];
    const float* bl1 = (const float*)d_in[11];
    const float* Wl2 = (const float*)d_in[12];
    const float* bl2 = (const float*)d_in[13];

    float* x_out    = (float*)d_out;                 // [B,N,C]
    float* mask_out = x_out + (size_t)B_ * N_ * C_;  // [B,N,L,1]

    char* w = (char*)d_ws;
    bf16*     WTq  = (bf16*)(w);
    bf16*     WTk  = (bf16*)(w + (128 << 10));
    bf16*     WTv  = (bf16*)(w + (256 << 10));
    bf16*     WTp  = (bf16*)(w + (384 << 10));
    h2*       mlpc = (h2*)(w + (512 << 10));         // 160B (64KB slot)
    bf16*     Qb   = (bf16*)(w + (576 << 10));       // 1MB
    bf16*     Kb   = (bf16*)(w + (1600 << 10));      // 4MB
    _Float16* Vt   = (_Float16*)(w + (5696 << 10));  // 4MB
    bf16*     xpre = (bf16*)(w + (1600 << 10));      // 1MB, aliases Kb (dead post-attn)
    bf16*     pacc = (bf16*)(w + (9792 << 10));      // NS MB

    const bool big = ws_size >= ((size_t)28224 << 10);
    const int NS = big ? 16 : 8;
    float* ps = (float*)(w + ((size_t)(9792 + NS * 1024) << 10));

    hipLaunchKernelGGL(wtrans_kernel, dim3(64), dim3(256), 0, stream,
                       Wq, Wk, Wv, Wp, Wl1, bl1, Wl2, WTq, WTk, WTv, WTp, mlpc);
    hipLaunchKernelGGL(proj_qkv_kernel, dim3(1152), dim3(256), 0, stream,
                       query, key, value, WTq, WTk, WTv, Qb, Kb, Vt);
    if (big) {
        attn_kernel<16><<<dim3(B_ * 32 * 16), dim3(512), 0, stream>>>(
            Qb, Kb, Vt, mlpc, bl2, pacc, ps, mask_out);
        combine_kernel<16><<<dim3(256), dim3(256), 0, stream>>>(pacc, ps, xpre);
    } else {
        attn_kernel<8><<<dim3(B_ * 32 * 8), dim3(512), 0, stream>>>(
            Qb, Kb, Vt, mlpc, bl2, pacc, ps, mask_out);
        combine_kernel<8><<<dim3(256), dim3(256), 0, stream>>>(pacc, ps, xpre);
    }
    hipLaunchKernelGGL(outproj_kernel, dim3(256), dim3(256), 0, stream,
                       xpre, WTp, bp, x_out);
}

// Round 18
// 63.068 us; speedup vs baseline: 1.1854x; 1.0548x over previous
//
#include <hip/hip_runtime.h>
#include <math.h>
#include <stdint.h>

typedef __bf16 bf16;
typedef __bf16 bfx8 __attribute__((ext_vector_type(8)));
typedef __bf16 bfx4 __attribute__((ext_vector_type(4)));
typedef short  sh8  __attribute__((ext_vector_type(8)));
typedef float  fx4  __attribute__((ext_vector_type(4)));
typedef _Float16 h2 __attribute__((ext_vector_type(2)));
typedef _Float16 hx4 __attribute__((ext_vector_type(4)));
typedef _Float16 h8 __attribute__((ext_vector_type(8)));

#define B_ 2
#define N_ 1024
#define L_ 4096
#define C_ 256
#define H_ 8
#define D_ 32
#define KL 32
#define LOG2E 1.4426950408889634f
#define LN2 0.6931471805599453f
#define QSCALE (0.17677669529663687f * LOG2E)   // 1/sqrt(32) * log2(e), folded into Q

__device__ __forceinline__ _Float16 exp2h(_Float16 x) {
    _Float16 r; asm("v_exp_f16 %0, %1" : "=v"(r) : "v"(x)); return r;
}
__device__ __forceinline__ h2 pkrtz(float a, float b) {
    return __builtin_bit_cast(h2, __builtin_amdgcn_cvt_pkrtz(a, b));
}

// ---------- single-barrier projection GEMM ----------
// B-panel staged directly from f32 W (transpose folded into the gather):
// b2s[(kc*BN + c)*8 + j] = (bf16)W[(kc*8+j)*256 + n0 + c]; each j-round is a
// coalesced 64-lane x 4B read. A rows read direct from global.
// MODE 0: bf16 out (scaled). MODE 1: f16 out transposed to Vt.
template<int MODE>
__device__ __forceinline__
void proj_fast(const float* __restrict__ X, const float* __restrict__ W,
               void* __restrict__ outp, int m0, int n0, float oscale, bf16* b2s) {
    const int tid = threadIdx.x;
    const int w = tid >> 6;
    const int lane = tid & 63;
    const int r = lane & 15;
    const int g = lane >> 4;

    #pragma unroll
    for (int p = 0; p < 8; ++p) {
        const int kc = (tid >> 6) + p * 4;
        const int c = tid & 63;
        const float* wsrc = W + (size_t)(kc * 8) * C_ + n0 + c;
        bfx8 v;
        #pragma unroll
        for (int j = 0; j < 8; ++j) v[j] = (bf16)wsrc[(size_t)j * C_];
        *(bfx8*)&b2s[(kc * 64 + c) * 8] = v;
    }
    __syncthreads();

    fx4 acc[4];
    #pragma unroll
    for (int t = 0; t < 4; ++t) acc[t] = (fx4){0.f, 0.f, 0.f, 0.f};

    const float* arow = X + (size_t)(m0 + w * 16 + r) * C_ + g * 8;
    #pragma unroll
    for (int kt = 0; kt < 8; ++kt) {
        const float4 x0 = *(const float4*)(arow + kt * 32);
        const float4 x1 = *(const float4*)(arow + kt * 32 + 4);
        bfx8 af;
        af[0] = (bf16)x0.x; af[1] = (bf16)x0.y; af[2] = (bf16)x0.z; af[3] = (bf16)x0.w;
        af[4] = (bf16)x1.x; af[5] = (bf16)x1.y; af[6] = (bf16)x1.z; af[7] = (bf16)x1.w;
        #pragma unroll
        for (int t = 0; t < 4; ++t) {
            const bfx8 bfr = *(const bfx8*)&b2s[((kt * 4 + g) * 64 + t * 16 + r) * 8];
            acc[t] = __builtin_amdgcn_mfma_f32_16x16x32_bf16(af, bfr, acc[t], 0, 0, 0);
        }
    }

    const int mb = m0 + w * 16;
    if (MODE == 0) {
        bf16* out = (bf16*)outp;
        #pragma unroll
        for (int t = 0; t < 4; ++t)
            #pragma unroll
            for (int reg = 0; reg < 4; ++reg)
                out[(size_t)(mb + 4 * g + reg) * C_ + n0 + t * 16 + r] = (bf16)(acc[t][reg] * oscale);
    } else {
        _Float16* out = (_Float16*)outp;   // Vt[b][h][d][l], f16
        const int bb = m0 >> 12;
        const int l0 = (m0 & (L_ - 1)) + w * 16 + 4 * g;
        #pragma unroll
        for (int t = 0; t < 4; ++t) {
            const int cc = n0 + t * 16 + r;
            hx4 v;
            #pragma unroll
            for (int reg = 0; reg < 4; ++reg) v[reg] = (_Float16)acc[t][reg];
            *(hx4*)(out + ((size_t)((bb * H_ + (cc >> 5)) * D_ + (cc & 31)) * L_ + l0)) = v;
        }
    }
}

// XCD-local mapping: within each segment, mtile = i % nm (nm % 8 == 0), coltile = i / nm,
// so the 4 blocks sharing the same A rows are ≡ mod 8 -> same XCD -> A hits local L2.
// Block 0 also preps the packed-h2 MLP constants (consumed by attn via s_load).
__global__ __launch_bounds__(256)
void proj_qkv_kernel(const float* __restrict__ q, const float* __restrict__ k,
                     const float* __restrict__ v,
                     const float* __restrict__ Wq, const float* __restrict__ Wk,
                     const float* __restrict__ Wv,
                     const float* __restrict__ Wl1, const float* __restrict__ bl1,
                     const float* __restrict__ Wl2,
                     bf16* __restrict__ Qb, bf16* __restrict__ Kb, _Float16* __restrict__ Vt,
                     h2* __restrict__ mlpc) {
    __shared__ __align__(16) bf16 b2s[32 * 64 * 8];   // 32KB
    const int bid = blockIdx.x;        // 1152 = 128 Q + 512 K + 512 V
    const int tid = threadIdx.x;
    if (bid == 0) {   // MLP consts: w1h[32] (x ln2), b1h[4], w2h[4]
        if (tid < 32) {
            const int hh = tid >> 2, jp = tid & 3;
            mlpc[tid] = (h2){(_Float16)(LN2 * Wl1[hh * 8 + 2 * jp]),
                             (_Float16)(LN2 * Wl1[hh * 8 + 2 * jp + 1])};
        }
        if (tid < 4) {
            mlpc[32 + tid] = (h2){(_Float16)bl1[2 * tid], (_Float16)bl1[2 * tid + 1]};
            mlpc[36 + tid] = (h2){(_Float16)Wl2[2 * tid], (_Float16)Wl2[2 * tid + 1]};
        }
    }
    if (bid < 128) {
        proj_fast<0>(q, Wq, Qb, (bid & 31) * 64, (bid >> 5) * 64, QSCALE, b2s);
    } else if (bid < 640) {
        const int i = bid - 128;
        proj_fast<0>(k, Wk, Kb, (i & 127) * 64, (i >> 7) * 64, 1.0f, b2s);
    } else {
        const int i = bid - 640;
        proj_fast<1>(v, Wv, Vt, (i & 127) * 64, (i >> 7) * 64, 1.0f, b2s);
    }
}

// ---------- split-L combine (plain sums; softmax uses fixed max=0) ----------
template<int NS>
__global__ __launch_bounds__(256)
void combine_kernel(const bf16* __restrict__ pacc, const float* __restrict__ ps,
                    bf16* __restrict__ xpre) {
    const int idx = blockIdx.x * 256 + threadIdx.x;   // 65536
    const int dg = idx & 3;
    const int row = idx >> 2;
    const int n = row & (N_ - 1);
    const int bh = row >> 10;
    const int b = bh >> 3, hh = bh & 7;
    float S = 0.f;
    float X[8];
    #pragma unroll
    for (int j = 0; j < 8; ++j) X[j] = 0.f;
    #pragma unroll
    for (int sp = 0; sp < NS; ++sp) {
        S += ps[(size_t)(bh * NS + sp) * N_ + n];
        const bfx8 pv = *(const bfx8*)(pacc + ((size_t)(bh * NS + sp) * N_ + n) * D_ + dg * 8);
        #pragma unroll
        for (int j = 0; j < 8; ++j) X[j] += (float)pv[j];
    }
    const float inv = 1.0f / S;
    bfx8 v;
    #pragma unroll
    for (int j = 0; j < 8; ++j) v[j] = (bf16)(X[j] * inv);
    *(bfx8*)(xpre + (size_t)(b * N_ + n) * C_ + hh * D_ + dg * 8) = v;
}

// ---------- single-barrier out-projection: BM=64 x BN=32, A = bf16 direct ----------
__global__ __launch_bounds__(256)
void outproj_kernel(const bf16* __restrict__ xpre, const float* __restrict__ Wp,
                    const float* __restrict__ bp, float* __restrict__ x_out) {
    __shared__ __align__(16) bf16 b2s[32 * 32 * 8];   // 16KB
    const int m0 = (blockIdx.x & 31) * 64;
    const int n0 = (blockIdx.x >> 5) * 32;
    const int tid = threadIdx.x;
    const int w = tid >> 6, lane = tid & 63, r = lane & 15, g = lane >> 4;

    #pragma unroll
    for (int p = 0; p < 4; ++p) {
        const int kc = (tid >> 5) + p * 8;
        const int c = tid & 31;
        const float* wsrc = Wp + (size_t)(kc * 8) * C_ + n0 + c;
        bfx8 v;
        #pragma unroll
        for (int j = 0; j < 8; ++j) v[j] = (bf16)wsrc[(size_t)j * C_];
        *(bfx8*)&b2s[(kc * 32 + c) * 8] = v;
    }
    __syncthreads();

    fx4 acc[2];
    acc[0] = (fx4){0.f, 0.f, 0.f, 0.f};
    acc[1] = (fx4){0.f, 0.f, 0.f, 0.f};
    const bf16* arow = xpre + (size_t)(m0 + w * 16 + r) * C_ + g * 8;
    #pragma unroll
    for (int kt = 0; kt < 8; ++kt) {
        const bfx8 af = *(const bfx8*)(arow + kt * 32);
        #pragma unroll
        for (int t = 0; t < 2; ++t) {
            const bfx8 bfr = *(const bfx8*)&b2s[((kt * 4 + g) * 32 + t * 16 + r) * 8];
            acc[t] = __builtin_amdgcn_mfma_f32_16x16x32_bf16(af, bfr, acc[t], 0, 0, 0);
        }
    }
    const int mb = m0 + w * 16;
    #pragma unroll
    for (int t = 0; t < 2; ++t) {
        const float bv = bp[n0 + t * 16 + r];
        #pragma unroll
        for (int reg = 0; reg < 4; ++reg)
            x_out[(size_t)(mb + 4 * g + reg) * C_ + n0 + t * 16 + r] = acc[t][reg] + bv;
    }
}

// ---------- fused attention (R14 configuration — empirical Pareto point) ----------
// grid B*32*NS; 8 waves = 8 heads; 32 q-rows (2 sub-tiles of 16).
// K staged in LDS (XOR swizzle): QK depends only on lgkmcnt, not vmcnt —
// direct-global K (R16) exposed L2 latency serialized behind the store queue.
// Fixed max=0 softmax; f16 exp/PV; per-lane row-sum partials, epilogue reduce;
// nontemporal maskout. NOTE: min-waves 4 (R9/R10: forcing 8 spills, +250MB
// scratch traffic). Keep VGPR <= 64 for 4-block/CU residency. MLP constants
// come via wave-uniform s_loads from mlpc (h2 in workspace) — NOT converted
// in-kernel (would cost ~40 VGPRs and halve occupancy).
template<int NS>
__global__ __launch_bounds__(512, 4)
void attn_kernel(const bf16* __restrict__ Qb, const bf16* __restrict__ Kb,
                 const _Float16* __restrict__ Vt,
                 const h2* __restrict__ mlpc, const float* __restrict__ bl2,
                 bf16* __restrict__ pacc, float* __restrict__ ps,
                 float* __restrict__ maskout) {
    constexpr int LSPAN = L_ / NS;
    constexpr int NIT = LSPAN / KL;
    const int bx = blockIdx.x;
    const int split = bx % NS;
    const int rest = bx / NS;
    const int nt = rest & 31;
    const int b = rest >> 5;
    const int n0 = nt * 32;
    const int l0base = split * LSPAN;

    const int tid = threadIdx.x;
    const int h = tid >> 6;
    const int lane = tid & 63;
    const int r = lane & 15;
    const int g = lane >> 4;

    __shared__ __align__(16) short k_lds[KL * C_];   // 16KB, XOR-swizzled rows
    __shared__ __align__(16) h2 s_lds[8 * 16 * 36];  // 18KB, (sub0,sub1) packed

    const float bl2v = bl2[0];
    h2 W1[32], B1[4], W2[4];
    #pragma unroll
    for (int i = 0; i < 32; ++i) W1[i] = mlpc[i];
    #pragma unroll
    for (int i = 0; i < 4; ++i) { B1[i] = mlpc[32 + i]; W2[i] = mlpc[36 + i]; }

    const bfx8 qa0 = *(const bfx8*)(Qb + ((size_t)(b * N_ + n0 + r) * C_ + h * D_ + g * 8));
    const bfx8 qa1 = *(const bfx8*)(Qb + ((size_t)(b * N_ + n0 + 16 + r) * C_ + h * D_ + g * 8));

    const int krow = tid >> 5;
    const int kcolb = (tid & 31) * 16;
    const char* Kbb = (const char*)(Kb + (size_t)b * L_ * C_);

    {   // prologue: stage K tile 0
        sh8 k0v = *(const sh8*)(Kbb + (size_t)(l0base + krow) * 512 + kcolb);
        sh8 k1v = *(const sh8*)(Kbb + (size_t)(l0base + 16 + krow) * 512 + kcolb);
        *(sh8*)((char*)k_lds + ((krow * 512 + kcolb) ^ ((krow & 7) << 4))) = k0v;
        *(sh8*)((char*)k_lds + (((krow + 16) * 512 + kcolb) ^ (((krow + 16) & 7) << 4))) = k1v;
    }

    const _Float16* Vb0 = Vt + (size_t)((b * H_ + h) * D_ + r) * L_ + g * 8;
    const _Float16* Vb1 = Vt + (size_t)((b * H_ + h) * D_ + 16 + r) * L_ + g * 8;
    h8 vc0 = *(const h8*)(Vb0 + l0base);
    h8 vc1 = *(const h8*)(Vb1 + l0base);

    float s0r = 0.f, s1r = 0.f;   // per-lane partial row sums (reduced in epilogue)
    fx4 accA0 = {0.f,0.f,0.f,0.f}, accA1 = {0.f,0.f,0.f,0.f};
    fx4 accB0 = {0.f,0.f,0.f,0.f}, accB1 = {0.f,0.f,0.f,0.f};

    const int mn = tid >> 5;
    const int ml = tid & 31;
    const int moff = mn * 36 + (ml ^ ((mn & 3) << 3));
    const int abase = h * 576 + r * 36 + ((g ^ (r & 3)) << 3);

    for (int it = 0; it < NIT; ++it) {
        const int l0 = l0base + it * KL;
        __syncthreads();   // (1) k_lds tile ready; prev s_lds reads done

        // ---- S = Q K^T (log2 domain) ----
        fx4 sA0, sA1, sB0, sB1;
        {
            const int byte0 = (r * 512 + h * 64 + g * 16) ^ ((r & 7) << 4);
            const int byte1 = ((r + 16) * 512 + h * 64 + g * 16) ^ (((r + 16) & 7) << 4);
            const bfx8 kb0 = __builtin_bit_cast(bfx8, *(const sh8*)((char*)k_lds + byte0));
            const bfx8 kb1 = __builtin_bit_cast(bfx8, *(const sh8*)((char*)k_lds + byte1));
            const fx4 z = {0.f, 0.f, 0.f, 0.f};
            __builtin_amdgcn_s_setprio(1);
            sA0 = __builtin_amdgcn_mfma_f32_16x16x32_bf16(qa0, kb0, z, 0, 0, 0);
            sA1 = __builtin_amdgcn_mfma_f32_16x16x32_bf16(qa0, kb1, z, 0, 0, 0);
            sB0 = __builtin_amdgcn_mfma_f32_16x16x32_bf16(qa1, kb0, z, 0, 0, 0);
            sB1 = __builtin_amdgcn_mfma_f32_16x16x32_bf16(qa1, kb1, z, 0, 0, 0);
            __builtin_amdgcn_s_setprio(0);
        }
        // publish S packed (sub0,sub1): rows n=4g+reg, cols r / r+16, col-XOR by (n&3)
        #pragma unroll
        for (int reg = 0; reg < 4; ++reg) {
            const int o = h * 576 + (4 * g + reg) * 36;
            const int xr = reg << 3;
            s_lds[o + ((r) ^ xr)]      = pkrtz(sA0[reg], sB0[reg]);
            s_lds[o + ((r + 16) ^ xr)] = pkrtz(sA1[reg], sB1[reg]);
        }
        __syncthreads();   // (2) s_lds ready; k_lds consumed

        // ---- issue next K + V global loads ----
        sh8 nk0, nk1;
        h8 nv0, nv1;
        const bool have_next = (it + 1 < NIT);
        if (have_next) {
            nk0 = *(const sh8*)(Kbb + (size_t)(l0 + KL + krow) * 512 + kcolb);
            nk1 = *(const sh8*)(Kbb + (size_t)(l0 + KL + 16 + krow) * 512 + kcolb);
            nv0 = *(const h8*)(Vb0 + l0 + KL);
            nv1 = *(const h8*)(Vb1 + l0 + KL);
        }

        // ---- mask MLP (packed f16, both subs per load) ----
        {
            h2 f0[4], f1[4];
            #pragma unroll
            for (int jp = 0; jp < 4; ++jp) { f0[jp] = B1[jp]; f1[jp] = B1[jp]; }
            #pragma unroll
            for (int hh = 0; hh < 8; ++hh) {
                const h2 sv = s_lds[hh * 576 + moff];
                const h2 s0h = (h2){sv[0], sv[0]};
                const h2 s1h = (h2){sv[1], sv[1]};
                #pragma unroll
                for (int jp = 0; jp < 4; ++jp) {
                    f0[jp] = s0h * W1[hh * 4 + jp] + f0[jp];
                    f1[jp] = s1h * W1[hh * 4 + jp] + f1[jp];
                }
            }
            const h2 z2 = (h2){(_Float16)0.f, (_Float16)0.f};
            h2 t0 = __builtin_elementwise_max(f0[0], z2) * W2[0];
            h2 t1 = __builtin_elementwise_max(f1[0], z2) * W2[0];
            #pragma unroll
            for (int jp = 1; jp < 4; ++jp) {
                t0 = __builtin_elementwise_max(f0[jp], z2) * W2[jp] + t0;
                t1 = __builtin_elementwise_max(f1[jp], z2) * W2[jp] + t1;
            }
            const float mk0 = fmaxf((float)t0[0] + (float)t0[1] + bl2v, 0.f);
            const float mk1 = fmaxf((float)t1[0] + (float)t1[1] + bl2v, 0.f);
            __builtin_nontemporal_store(mk0,
                &maskout[(size_t)(b * N_ + n0 + mn) * L_ + l0 + ml]);
            __builtin_nontemporal_store(mk1,
                &maskout[(size_t)(b * N_ + n0 + 16 + mn) * L_ + l0 + ml]);
        }

        // ---- A-layout S readback: row r, l = 8g..8g+7, both subs interleaved ----
        const h8 sv0 = *(const h8*)&s_lds[abase];       // (s0,s1) x l0..l3
        const h8 sv1 = *(const h8*)&s_lds[abase + 4];   // (s0,s1) x l4..l7

        // ---- softmax numerators, fixed max = 0: p = exp2(s), all in f16 ----
        h8 pa0, pa1;
        pa0[0] = exp2h(sv0[0]); pa0[1] = exp2h(sv0[2]);
        pa0[2] = exp2h(sv0[4]); pa0[3] = exp2h(sv0[6]);
        pa0[4] = exp2h(sv1[0]); pa0[5] = exp2h(sv1[2]);
        pa0[6] = exp2h(sv1[4]); pa0[7] = exp2h(sv1[6]);
        pa1[0] = exp2h(sv0[1]); pa1[1] = exp2h(sv0[3]);
        pa1[2] = exp2h(sv0[5]); pa1[3] = exp2h(sv0[7]);
        pa1[4] = exp2h(sv1[1]); pa1[5] = exp2h(sv1[3]);
        pa1[6] = exp2h(sv1[5]); pa1[7] = exp2h(sv1[7]);
        {   // packed partial sums -> per-lane accumulators (no shuffles in loop)
            const h2* c0 = (const h2*)&pa0;
            const h2* c1 = (const h2*)&pa1;
            const h2 q0 = (c0[0] + c0[1]) + (c0[2] + c0[3]);
            const h2 q1 = (c1[0] + c1[1]) + (c1[2] + c1[3]);
            s0r += (float)q0[0] + (float)q0[1];
            s1r += (float)q1[0] + (float)q1[1];
        }

        // ---- PV MFMAs (f16) ----
        __builtin_amdgcn_s_setprio(1);
        accA0 = __builtin_amdgcn_mfma_f32_16x16x32_f16(pa0, vc0, accA0, 0, 0, 0);
        accA1 = __builtin_amdgcn_mfma_f32_16x16x32_f16(pa0, vc1, accA1, 0, 0, 0);
        accB0 = __builtin_amdgcn_mfma_f32_16x16x32_f16(pa1, vc0, accB0, 0, 0, 0);
        accB1 = __builtin_amdgcn_mfma_f32_16x16x32_f16(pa1, vc1, accB1, 0, 0, 0);
        __builtin_amdgcn_s_setprio(0);

        if (have_next) {   // write next K tile; rotate V prefetch
            *(sh8*)((char*)k_lds + ((krow * 512 + kcolb) ^ ((krow & 7) << 4))) = nk0;
            *(sh8*)((char*)k_lds + (((krow + 16) * 512 + kcolb) ^ (((krow + 16) & 7) << 4))) = nk1;
            vc0 = nv0; vc1 = nv1;
        }
    }

    // ---- epilogue: single cross-lane row-sum reduce, then store partials ----
    s0r += __shfl_xor(s0r, 16, 64);
    s0r += __shfl_xor(s0r, 32, 64);
    s1r += __shfl_xor(s1r, 16, 64);
    s1r += __shfl_xor(s1r, 32, 64);

    const size_t pbase = (size_t)((b * H_ + h) * NS + split) * N_ + n0;
    #pragma unroll
    for (int reg = 0; reg < 4; ++reg) {
        const int n = 4 * g + reg;
        pacc[(pbase + n) * D_ + r]           = (bf16)accA0[reg];
        pacc[(pbase + n) * D_ + 16 + r]      = (bf16)accA1[reg];
        pacc[(pbase + 16 + n) * D_ + r]      = (bf16)accB0[reg];
        pacc[(pbase + 16 + n) * D_ + 16 + r] = (bf16)accB1[reg];
    }
    if (lane < 16) {
        ps[pbase + lane] = s0r;
        ps[pbase + 16 + lane] = s1r;
    }
}

// ---------- launch ----------
extern "C" void kernel_launch(void* const* d_in, const int* in_sizes, int n_in,
                              void* d_out, int out_size, void* d_ws, size_t ws_size,
                              hipStream_t stream) {
    const float* query = (const float*)d_in[0];
    const float* key   = (const float*)d_in[1];
    const float* value = (const float*)d_in[2];
    const float* Wq  = (const float*)d_in[5];
    const float* Wk  = (const float*)d_in[6];
    const float* Wv  = (const float*)d_in[7];
    const float* Wp  = (const float*)d_in[8];
    const float* bp  = (const float*)d_in[9];
    const float* Wl1 = (const float*)d_in[10];
    const float* bl1 = (const float*)d_in[11];
    const float* Wl2 = (const float*)d_in[12];
    const float* bl2 = (const float*)d_in[13];

    float* x_out    = (float*)d_out;                 // [B,N,C]
    float* mask_out = x_out + (size_t)B_ * N_ * C_;  // [B,N,L,1]

    char* w = (char*)d_ws;
    h2*       mlpc = (h2*)(w + (512 << 10));         // 160B (64KB slot)
    bf16*     Qb   = (bf16*)(w + (576 << 10));       // 1MB
    bf16*     Kb   = (bf16*)(w + (1600 << 10));      // 4MB
    _Float16* Vt   = (_Float16*)(w + (5696 << 10));  // 4MB
    bf16*     xpre = (bf16*)(w + (1600 << 10));      // 1MB, aliases Kb (dead post-attn)
    bf16*     pacc = (bf16*)(w + (9792 << 10));      // NS MB

    const bool big = ws_size >= ((size_t)28224 << 10);
    const int NS = big ? 16 : 8;
    float* ps = (float*)(w + ((size_t)(9792 + NS * 1024) << 10));

    hipLaunchKernelGGL(proj_qkv_kernel, dim3(1152), dim3(256), 0, stream,
                       query, key, value, Wq, Wk, Wv, Wl1, bl1, Wl2,
                       Qb, Kb, Vt, mlpc);
    if (big) {
        attn_kernel<16><<<dim3(B_ * 32 * 16), dim3(512), 0, stream>>>(
            Qb, Kb, Vt, mlpc, bl2, pacc, ps, mask_out);
        combine_kernel<16><<<dim3(256), dim3(256), 0, stream>>>(pacc, ps, xpre);
    } else {
        attn_kernel<8><<<dim3(B_ * 32 * 8), dim3(512), 0, stream>>>(
            Qb, Kb, Vt, mlpc, bl2, pacc, ps, mask_out);
        combine_kernel<8><<<dim3(256), dim3(256), 0, stream>>>(pacc, ps, xpre);
    }
    hipLaunchKernelGGL(outproj_kernel, dim3(256), dim3(256), 0, stream,
                       xpre, Wp, bp, x_out);
}

// Round 19
// 62.915 us; speedup vs baseline: 1.1883x; 1.0024x over previous
//
#include <hip/hip_runtime.h>
#include <math.h>
#include <stdint.h>

typedef __bf16 bf16;
typedef __bf16 bfx8 __attribute__((ext_vector_type(8)));
typedef __bf16 bfx4 __attribute__((ext_vector_type(4)));
typedef short  sh8  __attribute__((ext_vector_type(8)));
typedef float  fx4  __attribute__((ext_vector_type(4)));
typedef _Float16 h2 __attribute__((ext_vector_type(2)));
typedef _Float16 hx4 __attribute__((ext_vector_type(4)));
typedef _Float16 h8 __attribute__((ext_vector_type(8)));

#define B_ 2
#define N_ 1024
#define L_ 4096
#define C_ 256
#define H_ 8
#define D_ 32
#define KL 32
#define LOG2E 1.4426950408889634f
#define LN2 0.6931471805599453f
#define QSCALE (0.17677669529663687f * LOG2E)   // 1/sqrt(32) * log2(e), folded into Q

__device__ __forceinline__ _Float16 exp2h(_Float16 x) {
    _Float16 r; asm("v_exp_f16 %0, %1" : "=v"(r) : "v"(x)); return r;
}
__device__ __forceinline__ h2 pkrtz(float a, float b) {
    return __builtin_bit_cast(h2, __builtin_amdgcn_cvt_pkrtz(a, b));
}

// async global->LDS, 16B per lane; dest = wave-uniform base + lane*16 (linear)
#define GLOAD_LDS16(gsrc, ldst)                                                     \
    __builtin_amdgcn_global_load_lds(                                               \
        (const __attribute__((address_space(1))) void*)(gsrc),                      \
        (__attribute__((address_space(3))) void*)(ldst), 16, 0, 0)

// ---------- single-barrier projection GEMM ----------
// B-panel staged directly from f32 W (transpose folded into the gather).
// MODE 0: bf16 out (scaled). MODE 1: f16 out transposed to Vt.
template<int MODE>
__device__ __forceinline__
void proj_fast(const float* __restrict__ X, const float* __restrict__ W,
               void* __restrict__ outp, int m0, int n0, float oscale, bf16* b2s) {
    const int tid = threadIdx.x;
    const int w = tid >> 6;
    const int lane = tid & 63;
    const int r = lane & 15;
    const int g = lane >> 4;

    #pragma unroll
    for (int p = 0; p < 8; ++p) {
        const int kc = (tid >> 6) + p * 4;
        const int c = tid & 63;
        const float* wsrc = W + (size_t)(kc * 8) * C_ + n0 + c;
        bfx8 v;
        #pragma unroll
        for (int j = 0; j < 8; ++j) v[j] = (bf16)wsrc[(size_t)j * C_];
        *(bfx8*)&b2s[(kc * 64 + c) * 8] = v;
    }
    __syncthreads();

    fx4 acc[4];
    #pragma unroll
    for (int t = 0; t < 4; ++t) acc[t] = (fx4){0.f, 0.f, 0.f, 0.f};

    const float* arow = X + (size_t)(m0 + w * 16 + r) * C_ + g * 8;
    #pragma unroll
    for (int kt = 0; kt < 8; ++kt) {
        const float4 x0 = *(const float4*)(arow + kt * 32);
        const float4 x1 = *(const float4*)(arow + kt * 32 + 4);
        bfx8 af;
        af[0] = (bf16)x0.x; af[1] = (bf16)x0.y; af[2] = (bf16)x0.z; af[3] = (bf16)x0.w;
        af[4] = (bf16)x1.x; af[5] = (bf16)x1.y; af[6] = (bf16)x1.z; af[7] = (bf16)x1.w;
        #pragma unroll
        for (int t = 0; t < 4; ++t) {
            const bfx8 bfr = *(const bfx8*)&b2s[((kt * 4 + g) * 64 + t * 16 + r) * 8];
            acc[t] = __builtin_amdgcn_mfma_f32_16x16x32_bf16(af, bfr, acc[t], 0, 0, 0);
        }
    }

    const int mb = m0 + w * 16;
    if (MODE == 0) {
        bf16* out = (bf16*)outp;
        #pragma unroll
        for (int t = 0; t < 4; ++t)
            #pragma unroll
            for (int reg = 0; reg < 4; ++reg)
                out[(size_t)(mb + 4 * g + reg) * C_ + n0 + t * 16 + r] = (bf16)(acc[t][reg] * oscale);
    } else {
        _Float16* out = (_Float16*)outp;   // Vt[b][h][d][l], f16
        const int bb = m0 >> 12;
        const int l0 = (m0 & (L_ - 1)) + w * 16 + 4 * g;
        #pragma unroll
        for (int t = 0; t < 4; ++t) {
            const int cc = n0 + t * 16 + r;
            hx4 v;
            #pragma unroll
            for (int reg = 0; reg < 4; ++reg) v[reg] = (_Float16)acc[t][reg];
            *(hx4*)(out + ((size_t)((bb * H_ + (cc >> 5)) * D_ + (cc & 31)) * L_ + l0)) = v;
        }
    }
}

// XCD-local mapping: within each segment, mtile = i % nm (nm % 8 == 0), coltile = i / nm.
// Block 0 also preps the packed-h2 MLP constants (consumed by attn via s_load).
__global__ __launch_bounds__(256)
void proj_qkv_kernel(const float* __restrict__ q, const float* __restrict__ k,
                     const float* __restrict__ v,
                     const float* __restrict__ Wq, const float* __restrict__ Wk,
                     const float* __restrict__ Wv,
                     const float* __restrict__ Wl1, const float* __restrict__ bl1,
                     const float* __restrict__ Wl2,
                     bf16* __restrict__ Qb, bf16* __restrict__ Kb, _Float16* __restrict__ Vt,
                     h2* __restrict__ mlpc) {
    __shared__ __align__(16) bf16 b2s[32 * 64 * 8];   // 32KB
    const int bid = blockIdx.x;        // 1152 = 128 Q + 512 K + 512 V
    const int tid = threadIdx.x;
    if (bid == 0) {   // MLP consts: w1h[32] (x ln2), b1h[4], w2h[4]
        if (tid < 32) {
            const int hh = tid >> 2, jp = tid & 3;
            mlpc[tid] = (h2){(_Float16)(LN2 * Wl1[hh * 8 + 2 * jp]),
                             (_Float16)(LN2 * Wl1[hh * 8 + 2 * jp + 1])};
        }
        if (tid < 4) {
            mlpc[32 + tid] = (h2){(_Float16)bl1[2 * tid], (_Float16)bl1[2 * tid + 1]};
            mlpc[36 + tid] = (h2){(_Float16)Wl2[2 * tid], (_Float16)Wl2[2 * tid + 1]};
        }
    }
    if (bid < 128) {
        proj_fast<0>(q, Wq, Qb, (bid & 31) * 64, (bid >> 5) * 64, QSCALE, b2s);
    } else if (bid < 640) {
        const int i = bid - 128;
        proj_fast<0>(k, Wk, Kb, (i & 127) * 64, (i >> 7) * 64, 1.0f, b2s);
    } else {
        const int i = bid - 640;
        proj_fast<1>(v, Wv, Vt, (i & 127) * 64, (i >> 7) * 64, 1.0f, b2s);
    }
}

// ---------- split-L combine (plain sums; softmax uses fixed max=0) ----------
template<int NS>
__global__ __launch_bounds__(256)
void combine_kernel(const bf16* __restrict__ pacc, const float* __restrict__ ps,
                    bf16* __restrict__ xpre) {
    const int idx = blockIdx.x * 256 + threadIdx.x;   // 65536
    const int dg = idx & 3;
    const int row = idx >> 2;
    const int n = row & (N_ - 1);
    const int bh = row >> 10;
    const int b = bh >> 3, hh = bh & 7;
    float S = 0.f;
    float X[8];
    #pragma unroll
    for (int j = 0; j < 8; ++j) X[j] = 0.f;
    #pragma unroll
    for (int sp = 0; sp < NS; ++sp) {
        S += ps[(size_t)(bh * NS + sp) * N_ + n];
        const bfx8 pv = *(const bfx8*)(pacc + ((size_t)(bh * NS + sp) * N_ + n) * D_ + dg * 8);
        #pragma unroll
        for (int j = 0; j < 8; ++j) X[j] += (float)pv[j];
    }
    const float inv = 1.0f / S;
    bfx8 v;
    #pragma unroll
    for (int j = 0; j < 8; ++j) v[j] = (bf16)(X[j] * inv);
    *(bfx8*)(xpre + (size_t)(b * N_ + n) * C_ + hh * D_ + dg * 8) = v;
}

// ---------- single-barrier out-projection: BM=64 x BN=32, A = bf16 direct ----------
__global__ __launch_bounds__(256)
void outproj_kernel(const bf16* __restrict__ xpre, const float* __restrict__ Wp,
                    const float* __restrict__ bp, float* __restrict__ x_out) {
    __shared__ __align__(16) bf16 b2s[32 * 32 * 8];   // 16KB
    const int m0 = (blockIdx.x & 31) * 64;
    const int n0 = (blockIdx.x >> 5) * 32;
    const int tid = threadIdx.x;
    const int w = tid >> 6, lane = tid & 63, r = lane & 15, g = lane >> 4;

    #pragma unroll
    for (int p = 0; p < 4; ++p) {
        const int kc = (tid >> 5) + p * 8;
        const int c = tid & 31;
        const float* wsrc = Wp + (size_t)(kc * 8) * C_ + n0 + c;
        bfx8 v;
        #pragma unroll
        for (int j = 0; j < 8; ++j) v[j] = (bf16)wsrc[(size_t)j * C_];
        *(bfx8*)&b2s[(kc * 32 + c) * 8] = v;
    }
    __syncthreads();

    fx4 acc[2];
    acc[0] = (fx4){0.f, 0.f, 0.f, 0.f};
    acc[1] = (fx4){0.f, 0.f, 0.f, 0.f};
    const bf16* arow = xpre + (size_t)(m0 + w * 16 + r) * C_ + g * 8;
    #pragma unroll
    for (int kt = 0; kt < 8; ++kt) {
        const bfx8 af = *(const bfx8*)(arow + kt * 32);
        #pragma unroll
        for (int t = 0; t < 2; ++t) {
            const bfx8 bfr = *(const bfx8*)&b2s[((kt * 4 + g) * 32 + t * 16 + r) * 8];
            acc[t] = __builtin_amdgcn_mfma_f32_16x16x32_bf16(af, bfr, acc[t], 0, 0, 0);
        }
    }
    const int mb = m0 + w * 16;
    #pragma unroll
    for (int t = 0; t < 2; ++t) {
        const float bv = bp[n0 + t * 16 + r];
        #pragma unroll
        for (int reg = 0; reg < 4; ++reg)
            x_out[(size_t)(mb + 4 * g + reg) * C_ + n0 + t * 16 + r] = acc[t][reg] + bv;
    }
}

// ---------- fused attention (R14 Pareto config + async K staging) ----------
// grid B*32*NS; 8 waves = 8 heads; 32 q-rows (2 sub-tiles of 16).
// K staged via global_load_lds (width 16): LDS dest LINEAR (wave h covers rows
// {2h,2h+1} / {2h+16,2h+17} = uniform base + lane*16); the XOR bank-swizzle is
// pre-applied to the GLOBAL source column, so the existing swizzled reads see
// the same layout. __syncthreads drains vmcnt -> tile i+1 issued after barrier
// (2) of iter i lands before barrier (1) of iter i+1; all reads of tile i are
// complete at barrier (2). Fixed max=0 softmax; f16 exp/PV; per-lane row-sum
// partials; nontemporal maskout. min-waves 4 (spill guard); keep VGPR <= 64.
template<int NS>
__global__ __launch_bounds__(512, 4)
void attn_kernel(const bf16* __restrict__ Qb, const bf16* __restrict__ Kb,
                 const _Float16* __restrict__ Vt,
                 const h2* __restrict__ mlpc, const float* __restrict__ bl2,
                 bf16* __restrict__ pacc, float* __restrict__ ps,
                 float* __restrict__ maskout) {
    constexpr int LSPAN = L_ / NS;
    constexpr int NIT = LSPAN / KL;
    const int bx = blockIdx.x;
    const int split = bx % NS;
    const int rest = bx / NS;
    const int nt = rest & 31;
    const int b = rest >> 5;
    const int n0 = nt * 32;
    const int l0base = split * LSPAN;

    const int tid = threadIdx.x;
    const int h = tid >> 6;
    const int lane = tid & 63;
    const int r = lane & 15;
    const int g = lane >> 4;

    __shared__ __align__(16) short k_lds[KL * C_];   // 16KB, rows 512B, XOR layout
    __shared__ __align__(16) h2 s_lds[8 * 16 * 36];  // 18KB, (sub0,sub1) packed

    const float bl2v = bl2[0];
    h2 W1[32], B1[4], W2[4];
    #pragma unroll
    for (int i = 0; i < 32; ++i) W1[i] = mlpc[i];
    #pragma unroll
    for (int i = 0; i < 4; ++i) { B1[i] = mlpc[32 + i]; W2[i] = mlpc[36 + i]; }

    const bfx8 qa0 = *(const bfx8*)(Qb + ((size_t)(b * N_ + n0 + r) * C_ + h * D_ + g * 8));
    const bfx8 qa1 = *(const bfx8*)(Qb + ((size_t)(b * N_ + n0 + 16 + r) * C_ + h * D_ + g * 8));

    const char* Kbb = (const char*)(Kb + (size_t)b * L_ * C_);

    // async K staging geometry: wave h stages rows {2h,2h+1} and {2h+16,2h+17}
    const int sub = lane >> 5;
    const int lp  = (lane & 31) * 16;                 // byte col within row
    const int rA  = 2 * h + sub;                      // 0..15
    const int rB  = rA + 16;                          // 16..31
    const char* KsrcA = Kbb + rA * 512 + (lp ^ ((rA & 7) << 4));
    const char* KsrcB = Kbb + rB * 512 + (lp ^ ((rB & 7) << 4));
    short* KdstA = k_lds + (2 * h) * 256;             // wave-uniform, 1KB span
    short* KdstB = k_lds + (2 * h + 16) * 256;

    // prologue: stage K tile 0 (async)
    GLOAD_LDS16(KsrcA + (size_t)l0base * 512, KdstA);
    GLOAD_LDS16(KsrcB + (size_t)l0base * 512, KdstB);

    const _Float16* Vb0 = Vt + (size_t)((b * H_ + h) * D_ + r) * L_ + g * 8;
    const _Float16* Vb1 = Vt + (size_t)((b * H_ + h) * D_ + 16 + r) * L_ + g * 8;
    h8 vc0 = *(const h8*)(Vb0 + l0base);
    h8 vc1 = *(const h8*)(Vb1 + l0base);

    float s0r = 0.f, s1r = 0.f;   // per-lane partial row sums (reduced in epilogue)
    fx4 accA0 = {0.f,0.f,0.f,0.f}, accA1 = {0.f,0.f,0.f,0.f};
    fx4 accB0 = {0.f,0.f,0.f,0.f}, accB1 = {0.f,0.f,0.f,0.f};

    const int mn = tid >> 5;
    const int ml = tid & 31;
    const int moff = mn * 36 + (ml ^ ((mn & 3) << 3));
    const int abase = h * 576 + r * 36 + ((g ^ (r & 3)) << 3);

    for (int it = 0; it < NIT; ++it) {
        const int l0 = l0base + it * KL;
        __syncthreads();   // (1) drains vmcnt: k_lds tile ready; prev s_lds reads done

        // ---- S = Q K^T (log2 domain) ----
        fx4 sA0, sA1, sB0, sB1;
        {
            const int byte0 = (r * 512 + h * 64 + g * 16) ^ ((r & 7) << 4);
            const int byte1 = ((r + 16) * 512 + h * 64 + g * 16) ^ (((r + 16) & 7) << 4);
            const bfx8 kb0 = __builtin_bit_cast(bfx8, *(const sh8*)((char*)k_lds + byte0));
            const bfx8 kb1 = __builtin_bit_cast(bfx8, *(const sh8*)((char*)k_lds + byte1));
            const fx4 z = {0.f, 0.f, 0.f, 0.f};
            __builtin_amdgcn_s_setprio(1);
            sA0 = __builtin_amdgcn_mfma_f32_16x16x32_bf16(qa0, kb0, z, 0, 0, 0);
            sA1 = __builtin_amdgcn_mfma_f32_16x16x32_bf16(qa0, kb1, z, 0, 0, 0);
            sB0 = __builtin_amdgcn_mfma_f32_16x16x32_bf16(qa1, kb0, z, 0, 0, 0);
            sB1 = __builtin_amdgcn_mfma_f32_16x16x32_bf16(qa1, kb1, z, 0, 0, 0);
            __builtin_amdgcn_s_setprio(0);
        }
        // publish S packed (sub0,sub1): rows n=4g+reg, cols r / r+16, col-XOR by (n&3)
        #pragma unroll
        for (int reg = 0; reg < 4; ++reg) {
            const int o = h * 576 + (4 * g + reg) * 36;
            const int xr = reg << 3;
            s_lds[o + ((r) ^ xr)]      = pkrtz(sA0[reg], sB0[reg]);
            s_lds[o + ((r + 16) ^ xr)] = pkrtz(sA1[reg], sB1[reg]);
        }
        __syncthreads();   // (2) s_lds ready; all k_lds reads of tile it complete

        // ---- issue next K (async to LDS) + V prefetch (regs) ----
        h8 nv0, nv1;
        const bool have_next = (it + 1 < NIT);
        if (have_next) {
            GLOAD_LDS16(KsrcA + (size_t)(l0 + KL) * 512, KdstA);
            GLOAD_LDS16(KsrcB + (size_t)(l0 + KL) * 512, KdstB);
            nv0 = *(const h8*)(Vb0 + l0 + KL);
            nv1 = *(const h8*)(Vb1 + l0 + KL);
        }

        // ---- mask MLP (packed f16, both subs per load) ----
        {
            h2 f0[4], f1[4];
            #pragma unroll
            for (int jp = 0; jp < 4; ++jp) { f0[jp] = B1[jp]; f1[jp] = B1[jp]; }
            #pragma unroll
            for (int hh = 0; hh < 8; ++hh) {
                const h2 sv = s_lds[hh * 576 + moff];
                const h2 s0h = (h2){sv[0], sv[0]};
                const h2 s1h = (h2){sv[1], sv[1]};
                #pragma unroll
                for (int jp = 0; jp < 4; ++jp) {
                    f0[jp] = s0h * W1[hh * 4 + jp] + f0[jp];
                    f1[jp] = s1h * W1[hh * 4 + jp] + f1[jp];
                }
            }
            const h2 z2 = (h2){(_Float16)0.f, (_Float16)0.f};
            h2 t0 = __builtin_elementwise_max(f0[0], z2) * W2[0];
            h2 t1 = __builtin_elementwise_max(f1[0], z2) * W2[0];
            #pragma unroll
            for (int jp = 1; jp < 4; ++jp) {
                t0 = __builtin_elementwise_max(f0[jp], z2) * W2[jp] + t0;
                t1 = __builtin_elementwise_max(f1[jp], z2) * W2[jp] + t1;
            }
            const float mk0 = fmaxf((float)t0[0] + (float)t0[1] + bl2v, 0.f);
            const float mk1 = fmaxf((float)t1[0] + (float)t1[1] + bl2v, 0.f);
            __builtin_nontemporal_store(mk0,
                &maskout[(size_t)(b * N_ + n0 + mn) * L_ + l0 + ml]);
            __builtin_nontemporal_store(mk1,
                &maskout[(size_t)(b * N_ + n0 + 16 + mn) * L_ + l0 + ml]);
        }

        // ---- A-layout S readback: row r, l = 8g..8g+7, both subs interleaved ----
        const h8 sv0 = *(const h8*)&s_lds[abase];       // (s0,s1) x l0..l3
        const h8 sv1 = *(const h8*)&s_lds[abase + 4];   // (s0,s1) x l4..l7

        // ---- softmax numerators, fixed max = 0: p = exp2(s), all in f16 ----
        h8 pa0, pa1;
        pa0[0] = exp2h(sv0[0]); pa0[1] = exp2h(sv0[2]);
        pa0[2] = exp2h(sv0[4]); pa0[3] = exp2h(sv0[6]);
        pa0[4] = exp2h(sv1[0]); pa0[5] = exp2h(sv1[2]);
        pa0[6] = exp2h(sv1[4]); pa0[7] = exp2h(sv1[6]);
        pa1[0] = exp2h(sv0[1]); pa1[1] = exp2h(sv0[3]);
        pa1[2] = exp2h(sv0[5]); pa1[3] = exp2h(sv0[7]);
        pa1[4] = exp2h(sv1[1]); pa1[5] = exp2h(sv1[3]);
        pa1[6] = exp2h(sv1[5]); pa1[7] = exp2h(sv1[7]);
        {   // packed partial sums -> per-lane accumulators (no shuffles in loop)
            const h2* c0 = (const h2*)&pa0;
            const h2* c1 = (const h2*)&pa1;
            const h2 q0 = (c0[0] + c0[1]) + (c0[2] + c0[3]);
            const h2 q1 = (c1[0] + c1[1]) + (c1[2] + c1[3]);
            s0r += (float)q0[0] + (float)q0[1];
            s1r += (float)q1[0] + (float)q1[1];
        }

        // ---- PV MFMAs (f16) ----
        __builtin_amdgcn_s_setprio(1);
        accA0 = __builtin_amdgcn_mfma_f32_16x16x32_f16(pa0, vc0, accA0, 0, 0, 0);
        accA1 = __builtin_amdgcn_mfma_f32_16x16x32_f16(pa0, vc1, accA1, 0, 0, 0);
        accB0 = __builtin_amdgcn_mfma_f32_16x16x32_f16(pa1, vc0, accB0, 0, 0, 0);
        accB1 = __builtin_amdgcn_mfma_f32_16x16x32_f16(pa1, vc1, accB1, 0, 0, 0);
        __builtin_amdgcn_s_setprio(0);

        if (have_next) { vc0 = nv0; vc1 = nv1; }   // rotate V prefetch
    }

    // ---- epilogue: single cross-lane row-sum reduce, then store partials ----
    s0r += __shfl_xor(s0r, 16, 64);
    s0r += __shfl_xor(s0r, 32, 64);
    s1r += __shfl_xor(s1r, 16, 64);
    s1r += __shfl_xor(s1r, 32, 64);

    const size_t pbase = (size_t)((b * H_ + h) * NS + split) * N_ + n0;
    #pragma unroll
    for (int reg = 0; reg < 4; ++reg) {
        const int n = 4 * g + reg;
        pacc[(pbase + n) * D_ + r]           = (bf16)accA0[reg];
        pacc[(pbase + n) * D_ + 16 + r]      = (bf16)accA1[reg];
        pacc[(pbase + 16 + n) * D_ + r]      = (bf16)accB0[reg];
        pacc[(pbase + 16 + n) * D_ + 16 + r] = (bf16)accB1[reg];
    }
    if (lane < 16) {
        ps[pbase + lane] = s0r;
        ps[pbase + 16 + lane] = s1r;
    }
}

// ---------- launch ----------
extern "C" void kernel_launch(void* const* d_in, const int* in_sizes, int n_in,
                              void* d_out, int out_size, void* d_ws, size_t ws_size,
                              hipStream_t stream) {
    const float* query = (const float*)d_in[0];
    const float* key   = (const float*)d_in[1];
    const float* value = (const float*)d_in[2];
    const float* Wq  = (const float*)d_in[5];
    const float* Wk  = (const float*)d_in[6];
    const float* Wv  = (const float*)d_in[7];
    const float* Wp  = (const float*)d_in[8];
    const float* bp  = (const float*)d_in[9];
    const float* Wl1 = (const float*)d_in[10];
    const float* bl1 = (const float*)d_in[11];
    const float* Wl2 = (const float*)d_in[12];
    const float* bl2 = (const float*)d_in[13];

    float* x_out    = (float*)d_out;                 // [B,N,C]
    float* mask_out = x_out + (size_t)B_ * N_ * C_;  // [B,N,L,1]

    char* w = (char*)d_ws;
    h2*       mlpc = (h2*)(w + (512 << 10));         // 160B (64KB slot)
    bf16*     Qb   = (bf16*)(w + (576 << 10));       // 1MB
    bf16*     Kb   = (bf16*)(w + (1600 << 10));      // 4MB
    _Float16* Vt   = (_Float16*)(w + (5696 << 10));  // 4MB
    bf16*     xpre = (bf16*)(w + (1600 << 10));      // 1MB, aliases Kb (dead post-attn)
    bf16*     pacc = (bf16*)(w + (9792 << 10));      // NS MB

    const bool big = ws_size >= ((size_t)28224 << 10);
    const int NS = big ? 16 : 8;
    float* ps = (float*)(w + ((size_t)(9792 + NS * 1024) << 10));

    hipLaunchKernelGGL(proj_qkv_kernel, dim3(1152), dim3(256), 0, stream,
                       query, key, value, Wq, Wk, Wv, Wl1, bl1, Wl2,
                       Qb, Kb, Vt, mlpc);
    if (big) {
        attn_kernel<16><<<dim3(B_ * 32 * 16), dim3(512), 0, stream>>>(
            Qb, Kb, Vt, mlpc, bl2, pacc, ps, mask_out);
        combine_kernel<16><<<dim3(256), dim3(256), 0, stream>>>(pacc, ps, xpre);
    } else {
        attn_kernel<8><<<dim3(B_ * 32 * 8), dim3(512), 0, stream>>>(
            Qb, Kb, Vt, mlpc, bl2, pacc, ps, mask_out);
        combine_kernel<8><<<dim3(256), dim3(256), 0, stream>>>(pacc, ps, xpre);
    }
    hipLaunchKernelGGL(outproj_kernel, dim3(256), dim3(256), 0, stream,
                       xpre, Wp, bp, x_out);
}